// Round 2
// baseline (1925.591 us; speedup 1.0000x reference)
//
#include <hip/hip_runtime.h>
#include <math.h>

// ---------------- problem constants ----------------
#define D_MODEL   1024
#define D_INNER   2048
#define D_STATE   64
#define HEADDIM   128
#define NHEADS    16          // D_INNER / HEADDIM
#define D_CONV    4
#define CONV_DIM  2176        // D_INNER + 2*D_STATE
#define D_IN_PROJ 4240        // 2*D_INNER + 2*D_STATE + NHEADS
#define BATCH     2
#define SEQLEN    4096
#define RMS_EPS   1e-5f

#define LCHUNK    128
#define NCHUNK    (SEQLEN / LCHUNK)   // 32
#define SCAN_T    16                  // timesteps staged in LDS per barrier

// ---------------- fp32 NT GEMM: C[M,N] = A[M,K] * B[N,K]^T ----------------
// BM=128, BN=64, BK=16; 256 threads; 8x4 microtile/thread.
#define GBM 128
#define GBN 64
#define GBK 16

__launch_bounds__(256, 2)
__global__ void gemm_nt(const float* __restrict__ A, int lda,
                        const float* __restrict__ B,            // ldb == K
                        float* __restrict__ C, int ldc,
                        int M, int N, int K) {
  __shared__ float As[GBK][GBM + 4];
  __shared__ float Bs[GBK][GBN + 4];
  const int bm = blockIdx.y * GBM;
  const int bn = blockIdx.x * GBN;
  const int t  = threadIdx.x;
  const int ty = t >> 4;          // 0..15 -> M
  const int tx = t & 15;          // 0..15 -> N

  float acc[8][4];
#pragma unroll
  for (int i = 0; i < 8; ++i)
#pragma unroll
    for (int j = 0; j < 4; ++j) acc[i][j] = 0.f;

  const int ar = t >> 1;          // 0..127  (A row within tile)
  const int ak = (t & 1) * 8;     // 0 or 8
  const int br = t >> 2;          // 0..63   (B row within tile)
  const int bk = (t & 3) * 4;     // 0,4,8,12

  for (int k0 = 0; k0 < K; k0 += GBK) {
    const float* ap = A + (size_t)(bm + ar) * lda + k0 + ak;
    float4 a0 = *(const float4*)ap;
    float4 a1 = *(const float4*)(ap + 4);
    float4 b0;
    const int brow = bn + br;
    if (brow < N) b0 = *(const float4*)(B + (size_t)brow * K + k0 + bk);
    else          b0 = make_float4(0.f, 0.f, 0.f, 0.f);

    __syncthreads();  // protect previous iteration's reads
    As[ak + 0][ar] = a0.x; As[ak + 1][ar] = a0.y; As[ak + 2][ar] = a0.z; As[ak + 3][ar] = a0.w;
    As[ak + 4][ar] = a1.x; As[ak + 5][ar] = a1.y; As[ak + 6][ar] = a1.z; As[ak + 7][ar] = a1.w;
    Bs[bk + 0][br] = b0.x; Bs[bk + 1][br] = b0.y; Bs[bk + 2][br] = b0.z; Bs[bk + 3][br] = b0.w;
    __syncthreads();

#pragma unroll
    for (int k = 0; k < GBK; ++k) {
      float4 av0 = *(const float4*)&As[k][ty * 8];
      float4 av1 = *(const float4*)&As[k][ty * 8 + 4];
      float4 bv  = *(const float4*)&Bs[k][tx * 4];
      float am[8] = {av0.x, av0.y, av0.z, av0.w, av1.x, av1.y, av1.z, av1.w};
      float bb[4] = {bv.x, bv.y, bv.z, bv.w};
#pragma unroll
      for (int i = 0; i < 8; ++i)
#pragma unroll
        for (int j = 0; j < 4; ++j)
          acc[i][j] = fmaf(am[i], bb[j], acc[i][j]);
    }
  }

#pragma unroll
  for (int i = 0; i < 8; ++i) {
    const int row = bm + ty * 8 + i;
    const int col = bn + tx * 4;
    if (col < N) {  // N % 4 == 0 always -> whole float4 in-bounds when col < N
      *(float4*)(C + (size_t)row * ldc + col) =
          make_float4(acc[i][0], acc[i][1], acc[i][2], acc[i][3]);
    }
  }
}

// ---------------- dt = softplus(raw_dt + dt_bias), one batch ----------------
__global__ void dt_softplus(const float* __restrict__ zx,
                            const float* __restrict__ dt_bias,
                            float* __restrict__ dtb) {
  int idx = blockIdx.x * blockDim.x + threadIdx.x;
  if (idx >= SEQLEN * NHEADS) return;
  int h = idx & (NHEADS - 1);
  int l = idx >> 4;
  float x = zx[(size_t)l * D_IN_PROJ + (2 * D_INNER + 2 * D_STATE) + h] + dt_bias[h];
  dtb[idx] = (x > 20.f) ? x : log1pf(expf(x));
}

// ---------------- depthwise causal conv(4) + bias + SiLU, one batch ----------------
__global__ void conv_silu(const float* __restrict__ zx,
                          const float* __restrict__ cw,
                          const float* __restrict__ cb,
                          float* __restrict__ xc) {
  int idx = blockIdx.x * blockDim.x + threadIdx.x;
  if (idx >= SEQLEN * CONV_DIM) return;
  int c = idx % CONV_DIM;
  int l = idx / CONV_DIM;
  const float w0 = cw[c * 4 + 0], w1 = cw[c * 4 + 1], w2 = cw[c * 4 + 2], w3 = cw[c * 4 + 3];
  const float* base = zx + (size_t)l * D_IN_PROJ + D_INNER + c;
  float acc = cb[c];
  if (l >= 3) acc = fmaf(w0, base[-(ptrdiff_t)3 * D_IN_PROJ], acc);
  if (l >= 2) acc = fmaf(w1, base[-(ptrdiff_t)2 * D_IN_PROJ], acc);
  if (l >= 1) acc = fmaf(w2, base[-(ptrdiff_t)1 * D_IN_PROJ], acc);
  acc = fmaf(w3, base[0], acc);
  float sig = 1.f / (1.f + expf(-acc));
  xc[idx] = acc * sig;
}

// ---------------- chunked scan, pass A: local chunk states, one batch ----------------
// block = (h, c); thread t owns p = t>>2, n in [(t&3)*16, +16)
__launch_bounds__(512, 1)
__global__ void scan_passA(const float* __restrict__ xc,
                           const float* __restrict__ dtb,
                           const float* __restrict__ A_log,
                           float* __restrict__ Sc, float* __restrict__ Pc) {
  const int blk = blockIdx.x;          // h*NCHUNK + c
  const int c   = blk & (NCHUNK - 1);
  const int h   = blk / NCHUNK;
  const int t   = threadIdx.x;
  const int p   = t >> 2;
  const int n0  = (t & 3) * 16;
  const float Ah = -expf(A_log[h]);

  float s[16];
#pragma unroll
  for (int i = 0; i < 16; ++i) s[i] = 0.f;
  float dprod = 1.f;

  __shared__ float xs[SCAN_T][HEADDIM];
  __shared__ float Bsh[SCAN_T][D_STATE];
  __shared__ float dts[SCAN_T];

  const int l0 = c * LCHUNK;
  for (int jt = 0; jt < LCHUNK; jt += SCAN_T) {
    __syncthreads();
    for (int idx = t; idx < SCAN_T * HEADDIM; idx += 512) {
      int r = idx >> 7, col = idx & 127;
      int l = l0 + jt + r;
      xs[r][col] = xc[(size_t)l * CONV_DIM + h * HEADDIM + col];
    }
    for (int idx = t; idx < SCAN_T * D_STATE; idx += 512) {
      int r = idx >> 6, col = idx & 63;
      int l = l0 + jt + r;
      Bsh[r][col] = xc[(size_t)l * CONV_DIM + D_INNER + col];
    }
    if (t < SCAN_T) {
      int l = l0 + jt + t;
      dts[t] = dtb[(size_t)l * NHEADS + h];
    }
    __syncthreads();
#pragma unroll 4
    for (int j = 0; j < SCAN_T; ++j) {
      float a  = expf(dts[j] * Ah);
      float xp = xs[j][p];
      dprod *= a;
#pragma unroll
      for (int i = 0; i < 16; ++i)
        s[i] = fmaf(a, s[i], Bsh[j][n0 + i] * xp);
    }
  }
  float* sp = Sc + (size_t)blk * (HEADDIM * D_STATE) + p * D_STATE + n0;
#pragma unroll
  for (int i = 0; i < 16; i += 4)
    *(float4*)(sp + i) = make_float4(s[i], s[i + 1], s[i + 2], s[i + 3]);
  if (t == 0) Pc[blk] = dprod;
}

// ---------------- pass B: combine chunk states IN PLACE ----------------
// After this kernel, Sc[h,c] holds the INITIAL state for chunk c (exclusive prefix).
// Each thread owns its 16 elements exclusively -> read-then-write is race-free.
__launch_bounds__(512, 1)
__global__ void scan_passB(float* __restrict__ Sc, const float* __restrict__ Pc) {
  const int h = blockIdx.x;
  const int t = threadIdx.x;
  const int p  = t >> 2;
  const int n0 = (t & 3) * 16;
  float st[16];
#pragma unroll
  for (int i = 0; i < 16; ++i) st[i] = 0.f;
  for (int c = 0; c < NCHUNK; ++c) {
    size_t base = ((size_t)h * NCHUNK + c) * (HEADDIM * D_STATE) + p * D_STATE + n0;
    float P = Pc[(size_t)h * NCHUNK + c];
    float v[16];
#pragma unroll
    for (int i = 0; i < 16; i += 4) {
      float4 q = *(const float4*)(Sc + base + i);
      v[i] = q.x; v[i + 1] = q.y; v[i + 2] = q.z; v[i + 3] = q.w;
    }
#pragma unroll
    for (int i = 0; i < 16; i += 4)
      *(float4*)(Sc + base + i) = make_float4(st[i], st[i + 1], st[i + 2], st[i + 3]);
#pragma unroll
    for (int i = 0; i < 16; ++i)
      st[i] = fmaf(P, st[i], v[i]);
  }
}

// ---------------- pass C: re-scan with true init, emit y (+ D*x), one batch ----------
// y is written into zx's x-columns [D_INNER, 2*D_INNER) (dead after conv).
__launch_bounds__(512, 1)
__global__ void scan_passC(const float* __restrict__ xc,
                           const float* __restrict__ dtb,
                           const float* __restrict__ A_log,
                           const float* __restrict__ Dp,
                           const float* __restrict__ Sinit,   // == Sc after passB
                           float* __restrict__ zx) {
  const int blk = blockIdx.x;          // h*NCHUNK + c
  const int c   = blk & (NCHUNK - 1);
  const int h   = blk / NCHUNK;
  const int t   = threadIdx.x;
  const int p   = t >> 2;
  const int n0  = (t & 3) * 16;
  const float Ah = -expf(A_log[h]);
  const float Dh = Dp[h];

  float s[16];
  {
    const float* ip = Sinit + (size_t)blk * (HEADDIM * D_STATE) + p * D_STATE + n0;
#pragma unroll
    for (int i = 0; i < 16; i += 4) {
      float4 v = *(const float4*)(ip + i);
      s[i] = v.x; s[i + 1] = v.y; s[i + 2] = v.z; s[i + 3] = v.w;
    }
  }

  __shared__ float xs[SCAN_T][HEADDIM];
  __shared__ float Bsh[SCAN_T][D_STATE];
  __shared__ float Csh[SCAN_T][D_STATE];
  __shared__ float dts[SCAN_T];

  const int l0 = c * LCHUNK;
  for (int jt = 0; jt < LCHUNK; jt += SCAN_T) {
    __syncthreads();
    for (int idx = t; idx < SCAN_T * HEADDIM; idx += 512) {
      int r = idx >> 7, col = idx & 127;
      int l = l0 + jt + r;
      xs[r][col] = xc[(size_t)l * CONV_DIM + h * HEADDIM + col];
    }
    for (int idx = t; idx < SCAN_T * D_STATE * 2; idx += 512) {
      int r = idx / (D_STATE * 2), rem = idx % (D_STATE * 2);
      int l = l0 + jt + r;
      float v = xc[(size_t)l * CONV_DIM + D_INNER + rem];
      if (rem < D_STATE) Bsh[r][rem] = v;
      else               Csh[r][rem - D_STATE] = v;
    }
    if (t < SCAN_T) {
      int l = l0 + jt + t;
      dts[t] = dtb[(size_t)l * NHEADS + h];
    }
    __syncthreads();
    for (int j = 0; j < SCAN_T; ++j) {
      float a  = expf(dts[j] * Ah);
      float xp = xs[j][p];
      float part = 0.f;
#pragma unroll
      for (int i = 0; i < 16; ++i) {
        s[i] = fmaf(a, s[i], Bsh[j][n0 + i] * xp);
        part = fmaf(s[i], Csh[j][n0 + i], part);
      }
      part += __shfl_xor(part, 1);
      part += __shfl_xor(part, 2);
      if ((t & 3) == 0) {
        int l = l0 + jt + j;
        zx[(size_t)l * D_IN_PROJ + D_INNER + h * HEADDIM + p] = part + Dh * xp;
      }
    }
  }
}

// ---------------- RMSNorm + sigmoid(z) gate (in place on y columns), one batch -------
__launch_bounds__(256)
__global__ void rmsnorm_gate(float* __restrict__ zx, const float* __restrict__ rms_w) {
  const int row = blockIdx.x;
  const int t   = threadIdx.x;
  float* y       = zx + (size_t)row * D_IN_PROJ + D_INNER;
  const float* z = zx + (size_t)row * D_IN_PROJ;

  float4 a  = *(const float4*)(y + t * 8);
  float4 bq = *(const float4*)(y + t * 8 + 4);
  float ss = a.x * a.x + a.y * a.y + a.z * a.z + a.w * a.w +
             bq.x * bq.x + bq.y * bq.y + bq.z * bq.z + bq.w * bq.w;
#pragma unroll
  for (int off = 32; off > 0; off >>= 1) ss += __shfl_down(ss, off);
  __shared__ float red[4];
  if ((t & 63) == 0) red[t >> 6] = ss;
  __syncthreads();
  float tot = red[0] + red[1] + red[2] + red[3];
  float scale = rsqrtf(tot * (1.f / (float)D_INNER) + RMS_EPS);

  float vy[8] = {a.x, a.y, a.z, a.w, bq.x, bq.y, bq.z, bq.w};
#pragma unroll
  for (int jj = 0; jj < 8; ++jj) {
    int col = t * 8 + jj;
    float zv = z[col];
    float g = 1.f / (1.f + expf(-zv));
    vy[jj] = vy[jj] * scale * rms_w[col] * g;
  }
  *(float4*)(y + t * 8)     = make_float4(vy[0], vy[1], vy[2], vy[3]);
  *(float4*)(y + t * 8 + 4) = make_float4(vy[4], vy[5], vy[6], vy[7]);
}

// ---------------- launch: run the pipeline per batch, reusing workspace -------------
// ws peak = zx 17,367,040 + xc 8,912,896 + dtb 65,536 + Sc 4,194,304 + Pc 512 floats
//         = 30,540,288 floats = 122.2 MB   (previous 278 MB version presumably
//           overflowed d_ws -> device abort)
extern "C" void kernel_launch(void* const* d_in, const int* in_sizes, int n_in,
                              void* d_out, int out_size, void* d_ws, size_t ws_size,
                              hipStream_t stream) {
  const float* u         = (const float*)d_in[0];
  const float* in_proj_w = (const float*)d_in[1];
  const float* conv_w    = (const float*)d_in[2];
  const float* conv_b    = (const float*)d_in[3];
  const float* dt_bias   = (const float*)d_in[4];
  const float* A_log     = (const float*)d_in[5];
  const float* Dp        = (const float*)d_in[6];
  const float* rms_w     = (const float*)d_in[7];
  const float* out_w     = (const float*)d_in[8];
  float* out = (float*)d_out;

  float* ws  = (float*)d_ws;
  float* zx  = ws;                                            // [4096, 4240]
  float* xc  = zx  + (size_t)SEQLEN * D_IN_PROJ;              // [4096, 2176]
  float* dtb = xc  + (size_t)SEQLEN * CONV_DIM;               // [4096, 16]
  float* Sc  = dtb + (size_t)SEQLEN * NHEADS;                 // [16*32, 128*64]
  float* Pc  = Sc  + (size_t)NHEADS * NCHUNK * HEADDIM * D_STATE; // [512]

  for (int b = 0; b < BATCH; ++b) {
    const float* u_b  = u   + (size_t)b * SEQLEN * D_MODEL;
    float*      out_b = out + (size_t)b * SEQLEN * D_MODEL;

    // 1) in_proj GEMM: zx[4096, 4240] = u_b[4096,1024] * W^T
    dim3 g1((D_IN_PROJ + GBN - 1) / GBN, SEQLEN / GBM);
    gemm_nt<<<g1, 256, 0, stream>>>(u_b, D_MODEL, in_proj_w, zx, D_IN_PROJ,
                                    SEQLEN, D_IN_PROJ, D_MODEL);

    // 2) dt softplus
    dt_softplus<<<(SEQLEN * NHEADS + 255) / 256, 256, 0, stream>>>(zx, dt_bias, dtb);

    // 3) depthwise conv + SiLU
    conv_silu<<<(SEQLEN * CONV_DIM + 255) / 256, 256, 0, stream>>>(zx, conv_w, conv_b, xc);

    // 4-6) chunked scan (passB folds Sinit into Sc in place)
    scan_passA<<<NHEADS * NCHUNK, 512, 0, stream>>>(xc, dtb, A_log, Sc, Pc);
    scan_passB<<<NHEADS, 512, 0, stream>>>(Sc, Pc);
    scan_passC<<<NHEADS * NCHUNK, 512, 0, stream>>>(xc, dtb, A_log, Dp, Sc, zx);

    // 7) RMSNorm + gate (in place on y columns of zx)
    rmsnorm_gate<<<SEQLEN, 256, 0, stream>>>(zx, rms_w);

    // 8) out GEMM: out_b[4096,1024] = y[4096,2048] * out_w^T  (y at zx col 2048)
    dim3 g2(D_MODEL / GBN, SEQLEN / GBM);
    gemm_nt<<<g2, 256, 0, stream>>>(zx + D_INNER, D_IN_PROJ, out_w, out_b, D_MODEL,
                                    SEQLEN, D_MODEL, D_INNER);
  }
}

// Round 3
// 941.357 us; speedup vs baseline: 2.0455x; 2.0455x over previous
//
#include <hip/hip_runtime.h>
#include <math.h>

// ---------------- problem constants ----------------
#define D_MODEL   1024
#define D_INNER   2048
#define D_STATE   64
#define HEADDIM   128
#define NHEADS    16
#define D_CONV    4
#define CONV_DIM  2176        // D_INNER + 2*D_STATE
#define BATCH     2
#define SEQLEN    4096
#define RMS_EPS   1e-5f

// xbcdt buffer: cols [0,2048)=x, [2048,2112)=B, [2112,2176)=C, [2176,2192)=dt
#define XBC_LD    2192
#define DT_OFF    2176
#define N_XBC     2192
#define D_IN_PROJ 4240

#define LCHUNK    128
#define NCHUNK    (SEQLEN / LCHUNK)   // 32
#define SCAN_T    16

typedef __attribute__((ext_vector_type(8))) short short8;
typedef __attribute__((ext_vector_type(4))) float f32x4;

__device__ __forceinline__ ushort f2bf(float f) {
  unsigned u = __float_as_uint(f);
  u += 0x7fff + ((u >> 16) & 1);          // RNE
  return (ushort)(u >> 16);
}
__device__ __forceinline__ float bf2f(ushort h) {
  return __uint_as_float(((unsigned)h) << 16);
}

// ---------------- split fp32 -> bf16 hi/lo planes (weights, once per call) --------
__global__ void cvt_split(const float* __restrict__ w,
                          ushort* __restrict__ hi, ushort* __restrict__ lo, int n4) {
  int i = blockIdx.x * 256 + threadIdx.x;
  if (i >= n4) return;
  float4 v = ((const float4*)w)[i];
  ushort h0 = f2bf(v.x), h1 = f2bf(v.y), h2 = f2bf(v.z), h3 = f2bf(v.w);
  ushort l0 = f2bf(v.x - bf2f(h0)), l1 = f2bf(v.y - bf2f(h1));
  ushort l2 = f2bf(v.z - bf2f(h2)), l3 = f2bf(v.w - bf2f(h3));
  ((ushort4*)hi)[i] = make_ushort4(h0, h1, h2, h3);
  ((ushort4*)lo)[i] = make_ushort4(l0, l1, l2, l3);
}

// ---------------- split-bf16 MFMA NT GEMM: C[M,N] = A[M,K] * B[N,K]^T ------------
// A fp32 (split during staging); B pre-split bf16 hi/lo planes [N][K].
// BM x 128 x 32 tiles, 256 threads (4 waves in WRG x WCG grid), 3 MFMAs/tile pair.
template<int BM, int WRG>
__launch_bounds__(256, 2)
__global__ void gemm_bf16s(const float* __restrict__ A, int lda,
                           const ushort* __restrict__ Bh, const ushort* __restrict__ Bl,
                           float* __restrict__ C, int ldc,
                           int M, int N, int K) {
  constexpr int BN = 128, BK = 32;
  constexpr int WCG = 4 / WRG;
  constexpr int RT  = BM / (16 * WRG);     // row tiles per wave
  constexpr int CT  = BN / (16 * WCG);     // col tiles per wave
  constexpr int LDS_S = BK + 8;            // 40 ushorts: pad -> 2-way conflicts only
  constexpr int ANF4 = BM * (BK / 4) / 256;
  constexpr int BNS8 = BN * (BK / 8) / 256;

  __shared__ ushort Ah_s[BM * LDS_S], Al_s[BM * LDS_S];
  __shared__ ushort Bh_s[BN * LDS_S], Bl_s[BN * LDS_S];

  const int t    = threadIdx.x;
  const int bm   = blockIdx.y * BM;
  const int bn   = blockIdx.x * BN;
  const int wave = t >> 6, lane = t & 63;
  const int ml   = lane & 15, g4 = lane >> 4;
  const int wr   = wave % WRG, wc = wave / WRG;
  const int r0   = wr * RT * 16, c0 = wc * CT * 16;

  f32x4 acc[RT][CT];
#pragma unroll
  for (int i = 0; i < RT; ++i)
#pragma unroll
    for (int j = 0; j < CT; ++j) acc[i][j] = (f32x4){0.f, 0.f, 0.f, 0.f};

  for (int k0 = 0; k0 < K; k0 += BK) {
    // ---- global -> regs ----
    float4 areg[ANF4];
#pragma unroll
    for (int ii = 0; ii < ANF4; ++ii) {
      int idx = t + ii * 256, r = idx >> 3, c4 = idx & 7;
      areg[ii] = *(const float4*)(A + (size_t)(bm + r) * lda + k0 + c4 * 4);
    }
    short8 bregh[BNS8], bregl[BNS8];
#pragma unroll
    for (int ii = 0; ii < BNS8; ++ii) {
      int idx = t + ii * 256, r = idx >> 2, g = idx & 3;
      int brow = bn + r;
      if (brow < N) {
        size_t off = (size_t)brow * K + k0 + g * 8;
        bregh[ii] = *(const short8*)(Bh + off);
        bregl[ii] = *(const short8*)(Bl + off);
      } else {
        bregh[ii] = (short8){0, 0, 0, 0, 0, 0, 0, 0};
        bregl[ii] = (short8){0, 0, 0, 0, 0, 0, 0, 0};
      }
    }

    __syncthreads();   // previous iteration's LDS reads done
    // ---- regs -> LDS (split A on the fly) ----
#pragma unroll
    for (int ii = 0; ii < ANF4; ++ii) {
      int idx = t + ii * 256, r = idx >> 3, c4 = idx & 7;
      float4 v = areg[ii];
      ushort h0 = f2bf(v.x), h1 = f2bf(v.y), h2 = f2bf(v.z), h3 = f2bf(v.w);
      ushort l0 = f2bf(v.x - bf2f(h0)), l1 = f2bf(v.y - bf2f(h1));
      ushort l2 = f2bf(v.z - bf2f(h2)), l3 = f2bf(v.w - bf2f(h3));
      int off = r * LDS_S + c4 * 4;
      *(ushort4*)&Ah_s[off] = make_ushort4(h0, h1, h2, h3);
      *(ushort4*)&Al_s[off] = make_ushort4(l0, l1, l2, l3);
    }
#pragma unroll
    for (int ii = 0; ii < BNS8; ++ii) {
      int idx = t + ii * 256, r = idx >> 2, g = idx & 3;
      int off = r * LDS_S + g * 8;
      *(short8*)&Bh_s[off] = bregh[ii];
      *(short8*)&Bl_s[off] = bregl[ii];
    }
    __syncthreads();

    // ---- fragments + MFMA ----
    short8 ah[RT], al[RT], bh[CT], bl[CT];
#pragma unroll
    for (int i = 0; i < RT; ++i) {
      int off = (r0 + i * 16 + ml) * LDS_S + g4 * 8;
      ah[i] = *(const short8*)&Ah_s[off];
      al[i] = *(const short8*)&Al_s[off];
    }
#pragma unroll
    for (int j = 0; j < CT; ++j) {
      int off = (c0 + j * 16 + ml) * LDS_S + g4 * 8;
      bh[j] = *(const short8*)&Bh_s[off];
      bl[j] = *(const short8*)&Bl_s[off];
    }
#pragma unroll
    for (int i = 0; i < RT; ++i)
#pragma unroll
      for (int j = 0; j < CT; ++j) {
        acc[i][j] = __builtin_amdgcn_mfma_f32_16x16x32_bf16(ah[i], bh[j], acc[i][j], 0, 0, 0);
        acc[i][j] = __builtin_amdgcn_mfma_f32_16x16x32_bf16(ah[i], bl[j], acc[i][j], 0, 0, 0);
        acc[i][j] = __builtin_amdgcn_mfma_f32_16x16x32_bf16(al[i], bh[j], acc[i][j], 0, 0, 0);
      }
  }

  // ---- epilogue: C/D layout col=lane&15, row=(lane>>4)*4+reg ----
#pragma unroll
  for (int i = 0; i < RT; ++i)
#pragma unroll
    for (int j = 0; j < CT; ++j) {
      int col = bn + c0 + j * 16 + ml;
      if (col < N) {
        int rowb = bm + r0 + i * 16 + g4 * 4;
#pragma unroll
        for (int r = 0; r < 4; ++r)
          C[(size_t)(rowb + r) * ldc + col] = acc[i][j][r];
      }
    }
}

// ---------------- dt = softplus(raw_dt + dt_bias), one batch ----------------
__global__ void dt_softplus(const float* __restrict__ xbcdt,
                            const float* __restrict__ dt_bias,
                            float* __restrict__ dtb) {
  int idx = blockIdx.x * blockDim.x + threadIdx.x;
  if (idx >= SEQLEN * NHEADS) return;
  int h = idx & (NHEADS - 1);
  int l = idx >> 4;
  float x = xbcdt[(size_t)l * XBC_LD + DT_OFF + h] + dt_bias[h];
  dtb[idx] = (x > 20.f) ? x : log1pf(expf(x));
}

// ---------------- depthwise causal conv(4) + bias + SiLU, one batch ----------------
__global__ void conv_silu(const float* __restrict__ xbcdt,
                          const float* __restrict__ cw,
                          const float* __restrict__ cb,
                          float* __restrict__ xc) {
  int idx = blockIdx.x * blockDim.x + threadIdx.x;
  if (idx >= SEQLEN * CONV_DIM) return;
  int c = idx % CONV_DIM;
  int l = idx / CONV_DIM;
  const float w0 = cw[c * 4 + 0], w1 = cw[c * 4 + 1], w2 = cw[c * 4 + 2], w3 = cw[c * 4 + 3];
  const float* base = xbcdt + (size_t)l * XBC_LD + c;
  float acc = cb[c];
  if (l >= 3) acc = fmaf(w0, base[-(ptrdiff_t)3 * XBC_LD], acc);
  if (l >= 2) acc = fmaf(w1, base[-(ptrdiff_t)2 * XBC_LD], acc);
  if (l >= 1) acc = fmaf(w2, base[-(ptrdiff_t)1 * XBC_LD], acc);
  acc = fmaf(w3, base[0], acc);
  float sig = 1.f / (1.f + expf(-acc));
  xc[idx] = acc * sig;
}

// ---------------- chunked scan, pass A ----------------
__launch_bounds__(512, 1)
__global__ void scan_passA(const float* __restrict__ xc,
                           const float* __restrict__ dtb,
                           const float* __restrict__ A_log,
                           float* __restrict__ Sc, float* __restrict__ Pc) {
  const int blk = blockIdx.x;
  const int c   = blk & (NCHUNK - 1);
  const int h   = blk / NCHUNK;
  const int t   = threadIdx.x;
  const int p   = t >> 2;
  const int n0  = (t & 3) * 16;
  const float Ah = -expf(A_log[h]);

  float s[16];
#pragma unroll
  for (int i = 0; i < 16; ++i) s[i] = 0.f;
  float dprod = 1.f;

  __shared__ float xs[SCAN_T][HEADDIM];
  __shared__ float Bsh[SCAN_T][D_STATE];
  __shared__ float dts[SCAN_T];

  const int l0 = c * LCHUNK;
  for (int jt = 0; jt < LCHUNK; jt += SCAN_T) {
    __syncthreads();
    for (int idx = t; idx < SCAN_T * HEADDIM; idx += 512) {
      int r = idx >> 7, col = idx & 127;
      int l = l0 + jt + r;
      xs[r][col] = xc[(size_t)l * CONV_DIM + h * HEADDIM + col];
    }
    for (int idx = t; idx < SCAN_T * D_STATE; idx += 512) {
      int r = idx >> 6, col = idx & 63;
      int l = l0 + jt + r;
      Bsh[r][col] = xc[(size_t)l * CONV_DIM + D_INNER + col];
    }
    if (t < SCAN_T) {
      int l = l0 + jt + t;
      dts[t] = dtb[(size_t)l * NHEADS + h];
    }
    __syncthreads();
#pragma unroll 4
    for (int j = 0; j < SCAN_T; ++j) {
      float a  = expf(dts[j] * Ah);
      float xp = xs[j][p];
      dprod *= a;
#pragma unroll
      for (int i = 0; i < 16; ++i)
        s[i] = fmaf(a, s[i], Bsh[j][n0 + i] * xp);
    }
  }
  float* sp = Sc + (size_t)blk * (HEADDIM * D_STATE) + p * D_STATE + n0;
#pragma unroll
  for (int i = 0; i < 16; i += 4)
    *(float4*)(sp + i) = make_float4(s[i], s[i + 1], s[i + 2], s[i + 3]);
  if (t == 0) Pc[blk] = dprod;
}

// ---------------- pass B: exclusive prefix over chunks, in place, parallel -------
// grid (NHEADS, 16), block 512: each thread owns one state element, walks chunks.
__global__ void scan_passB(float* __restrict__ Sc, const float* __restrict__ Pc) {
  const int h = blockIdx.x;
  const int e = blockIdx.y * 512 + threadIdx.x;   // 0..8191
  const size_t hb = (size_t)h * NCHUNK;
  float st = 0.f;
  for (int c = 0; c < NCHUNK; ++c) {
    size_t idx = (hb + c) * (HEADDIM * D_STATE) + e;
    float P = Pc[hb + c];
    float v = Sc[idx];
    Sc[idx] = st;
    st = fmaf(P, st, v);
  }
}

// ---------------- pass C: re-scan with true init, emit y (+ D*x) ----------------
// y written into xbcdt x-columns [0, 2048) (dead after conv).
__launch_bounds__(512, 1)
__global__ void scan_passC(const float* __restrict__ xc,
                           const float* __restrict__ dtb,
                           const float* __restrict__ A_log,
                           const float* __restrict__ Dp,
                           const float* __restrict__ Sinit,   // == Sc after passB
                           float* __restrict__ xbcdt) {
  const int blk = blockIdx.x;
  const int c   = blk & (NCHUNK - 1);
  const int h   = blk / NCHUNK;
  const int t   = threadIdx.x;
  const int p   = t >> 2;
  const int n0  = (t & 3) * 16;
  const float Ah = -expf(A_log[h]);
  const float Dh = Dp[h];

  float s[16];
  {
    const float* ip = Sinit + (size_t)blk * (HEADDIM * D_STATE) + p * D_STATE + n0;
#pragma unroll
    for (int i = 0; i < 16; i += 4) {
      float4 v = *(const float4*)(ip + i);
      s[i] = v.x; s[i + 1] = v.y; s[i + 2] = v.z; s[i + 3] = v.w;
    }
  }

  __shared__ float xs[SCAN_T][HEADDIM];
  __shared__ float Bsh[SCAN_T][D_STATE];
  __shared__ float Csh[SCAN_T][D_STATE];
  __shared__ float dts[SCAN_T];

  const int l0 = c * LCHUNK;
  for (int jt = 0; jt < LCHUNK; jt += SCAN_T) {
    __syncthreads();
    for (int idx = t; idx < SCAN_T * HEADDIM; idx += 512) {
      int r = idx >> 7, col = idx & 127;
      int l = l0 + jt + r;
      xs[r][col] = xc[(size_t)l * CONV_DIM + h * HEADDIM + col];
    }
    for (int idx = t; idx < SCAN_T * D_STATE * 2; idx += 512) {
      int r = idx / (D_STATE * 2), rem = idx % (D_STATE * 2);
      int l = l0 + jt + r;
      float v = xc[(size_t)l * CONV_DIM + D_INNER + rem];
      if (rem < D_STATE) Bsh[r][rem] = v;
      else               Csh[r][rem - D_STATE] = v;
    }
    if (t < SCAN_T) {
      int l = l0 + jt + t;
      dts[t] = dtb[(size_t)l * NHEADS + h];
    }
    __syncthreads();
    for (int j = 0; j < SCAN_T; ++j) {
      float a  = expf(dts[j] * Ah);
      float xp = xs[j][p];
      float part = 0.f;
#pragma unroll
      for (int i = 0; i < 16; ++i) {
        s[i] = fmaf(a, s[i], Bsh[j][n0 + i] * xp);
        part = fmaf(s[i], Csh[j][n0 + i], part);
      }
      part += __shfl_xor(part, 1);
      part += __shfl_xor(part, 2);
      if ((t & 3) == 0) {
        int l = l0 + jt + j;
        xbcdt[(size_t)l * XBC_LD + h * HEADDIM + p] = part + Dh * xp;
      }
    }
  }
}

// ---------------- RMSNorm + sigmoid(z) gate (y in xbcdt, z in zbuf) ----------------
__launch_bounds__(256)
__global__ void rmsnorm_gate(float* __restrict__ xbcdt, const float* __restrict__ zbuf,
                             const float* __restrict__ rms_w) {
  const int row = blockIdx.x;
  const int t   = threadIdx.x;
  float* y       = xbcdt + (size_t)row * XBC_LD;
  const float* z = zbuf  + (size_t)row * D_INNER;

  float4 a  = *(const float4*)(y + t * 8);
  float4 bq = *(const float4*)(y + t * 8 + 4);
  float ss = a.x * a.x + a.y * a.y + a.z * a.z + a.w * a.w +
             bq.x * bq.x + bq.y * bq.y + bq.z * bq.z + bq.w * bq.w;
#pragma unroll
  for (int off = 32; off > 0; off >>= 1) ss += __shfl_down(ss, off);
  __shared__ float red[4];
  if ((t & 63) == 0) red[t >> 6] = ss;
  __syncthreads();
  float tot = red[0] + red[1] + red[2] + red[3];
  float scale = rsqrtf(tot * (1.f / (float)D_INNER) + RMS_EPS);

  float vy[8] = {a.x, a.y, a.z, a.w, bq.x, bq.y, bq.z, bq.w};
#pragma unroll
  for (int jj = 0; jj < 8; ++jj) {
    int col = t * 8 + jj;
    float zv = z[col];
    float g = 1.f / (1.f + expf(-zv));
    vy[jj] = vy[jj] * scale * rms_w[col] * g;
  }
  *(float4*)(y + t * 8)     = make_float4(vy[0], vy[1], vy[2], vy[3]);
  *(float4*)(y + t * 8 + 4) = make_float4(vy[4], vy[5], vy[6], vy[7]);
}

// ---------------- launch ----------------
// ws (floats): xbcdt 8,978,432 + xc 8,912,896 (reused for z after scan) + dtb 65,536
//            + Sc 4,194,304 + Pc 512 + w1 planes 4,341,760 + w2 planes 2,097,152
//            = 28,590,592 floats = 114.4 MB  (< 122 MB known-good)
extern "C" void kernel_launch(void* const* d_in, const int* in_sizes, int n_in,
                              void* d_out, int out_size, void* d_ws, size_t ws_size,
                              hipStream_t stream) {
  const float* u         = (const float*)d_in[0];
  const float* in_proj_w = (const float*)d_in[1];
  const float* conv_w    = (const float*)d_in[2];
  const float* conv_b    = (const float*)d_in[3];
  const float* dt_bias   = (const float*)d_in[4];
  const float* A_log     = (const float*)d_in[5];
  const float* Dp        = (const float*)d_in[6];
  const float* rms_w     = (const float*)d_in[7];
  const float* out_w     = (const float*)d_in[8];
  float* out = (float*)d_out;

  float* ws     = (float*)d_ws;
  float* xbcdt  = ws;                                          // [4096, 2192]
  float* xc     = xbcdt + (size_t)SEQLEN * XBC_LD;             // [4096, 2176]; later z [4096,2048]
  float* dtb    = xc    + (size_t)SEQLEN * CONV_DIM;           // [4096, 16]
  float* Sc     = dtb   + (size_t)SEQLEN * NHEADS;             // [512, 8192]
  float* Pc     = Sc    + (size_t)NHEADS * NCHUNK * HEADDIM * D_STATE; // [512]
  ushort* w1h   = (ushort*)(Pc + NHEADS * NCHUNK);             // [4240, 1024]
  ushort* w1l   = w1h + (size_t)D_IN_PROJ * D_MODEL;
  ushort* w2h   = w1l + (size_t)D_IN_PROJ * D_MODEL;           // [1024, 2048]
  ushort* w2l   = w2h + (size_t)D_MODEL * D_INNER;
  float* zbuf   = xc;                                          // alias (z after scan)

  // weight split (once per call)
  {
    int n4 = D_IN_PROJ * D_MODEL / 4;
    cvt_split<<<(n4 + 255) / 256, 256, 0, stream>>>(in_proj_w, w1h, w1l, n4);
    int m4 = D_MODEL * D_INNER / 4;
    cvt_split<<<(m4 + 255) / 256, 256, 0, stream>>>(out_w, w2h, w2l, m4);
  }

  for (int b = 0; b < BATCH; ++b) {
    const float* u_b  = u   + (size_t)b * SEQLEN * D_MODEL;
    float*      out_b = out + (size_t)b * SEQLEN * D_MODEL;

    // 1) xBC|dt GEMM: xbcdt[4096,2192] = u_b * in_proj_w[2048:4240]^T
    {
      const ushort* bh = w1h + (size_t)D_INNER * D_MODEL;
      const ushort* bl = w1l + (size_t)D_INNER * D_MODEL;
      dim3 g((N_XBC + 127) / 128, SEQLEN / 128);
      gemm_bf16s<128, 2><<<g, 256, 0, stream>>>(u_b, D_MODEL, bh, bl,
                                                xbcdt, XBC_LD, SEQLEN, N_XBC, D_MODEL);
    }

    // 2) dt softplus
    dt_softplus<<<(SEQLEN * NHEADS + 255) / 256, 256, 0, stream>>>(xbcdt, dt_bias, dtb);

    // 3) depthwise conv + SiLU
    conv_silu<<<(SEQLEN * CONV_DIM + 255) / 256, 256, 0, stream>>>(xbcdt, conv_w, conv_b, xc);

    // 4-6) chunked scan (y lands in xbcdt cols [0,2048))
    scan_passA<<<NHEADS * NCHUNK, 512, 0, stream>>>(xc, dtb, A_log, Sc, Pc);
    scan_passB<<<dim3(NHEADS, (HEADDIM * D_STATE) / 512), 512, 0, stream>>>(Sc, Pc);
    scan_passC<<<NHEADS * NCHUNK, 512, 0, stream>>>(xc, dtb, A_log, Dp, Sc, xbcdt);

    // 5) deferred z GEMM into the (now dead) conv buffer
    {
      dim3 g(D_INNER / 128, SEQLEN / 128);
      gemm_bf16s<128, 2><<<g, 256, 0, stream>>>(u_b, D_MODEL, w1h, w1l,
                                                zbuf, D_INNER, SEQLEN, D_INNER, D_MODEL);
    }

    // 7) RMSNorm + gate (in place on y)
    rmsnorm_gate<<<SEQLEN, 256, 0, stream>>>(xbcdt, zbuf, rms_w);

    // 8) out GEMM: out_b[4096,1024] = y[4096,2048] * out_w^T  (BM=64 -> 512 blocks)
    {
      dim3 g(D_MODEL / 128, SEQLEN / 64);
      gemm_bf16s<64, 1><<<g, 256, 0, stream>>>(xbcdt, XBC_LD, w2h, w2l,
                                               out_b, D_MODEL, SEQLEN, D_MODEL, D_INNER);
    }
  }
}

// Round 4
// 856.574 us; speedup vs baseline: 2.2480x; 1.0990x over previous
//
#include <hip/hip_runtime.h>
#include <math.h>

// ---------------- problem constants ----------------
#define D_MODEL   1024
#define D_INNER   2048
#define D_STATE   64
#define HEADDIM   128
#define NHEADS    16
#define D_CONV    4
#define CONV_DIM  2176        // D_INNER + 2*D_STATE
#define BATCH     2
#define SEQLEN    4096
#define RMS_EPS   1e-5f

// xbcdt buffer: cols [0,2048)=x, [2048,2112)=B, [2112,2176)=C, [2176,2192)=dt
#define XBC_LD    2192
#define DT_OFF    2176
#define N_XBC     2192
#define D_IN_PROJ 4240

#define LCHUNK    128
#define NCHUNK    (SEQLEN / LCHUNK)   // 32
#define SCAN_T    16

typedef __attribute__((ext_vector_type(8))) short short8;
typedef __attribute__((ext_vector_type(4))) float f32x4;

__device__ __forceinline__ ushort f2bf(float f) {
  unsigned u = __float_as_uint(f);
  u += 0x7fff + ((u >> 16) & 1);          // RNE
  return (ushort)(u >> 16);
}
__device__ __forceinline__ float bf2f(ushort h) {
  return __uint_as_float(((unsigned)h) << 16);
}

// async global->LDS, 16B per lane (global_load_lds_dwordx4)
__device__ __forceinline__ void gl_lds16(const ushort* g, ushort* l) {
  __builtin_amdgcn_global_load_lds(
      (const __attribute__((address_space(1))) unsigned int*)g,
      (__attribute__((address_space(3))) unsigned int*)l, 16, 0, 0);
}

// ---------------- split fp32 -> bf16 hi/lo planes ----------------
__global__ void cvt_split(const float* __restrict__ w,
                          ushort* __restrict__ hi, ushort* __restrict__ lo, int n4) {
  int i = blockIdx.x * 256 + threadIdx.x;
  if (i >= n4) return;
  float4 v = ((const float4*)w)[i];
  ushort h0 = f2bf(v.x), h1 = f2bf(v.y), h2 = f2bf(v.z), h3 = f2bf(v.w);
  ushort l0 = f2bf(v.x - bf2f(h0)), l1 = f2bf(v.y - bf2f(h1));
  ushort l2 = f2bf(v.z - bf2f(h2)), l3 = f2bf(v.w - bf2f(h3));
  ((ushort4*)hi)[i] = make_ushort4(h0, h1, h2, h3);
  ((ushort4*)lo)[i] = make_ushort4(l0, l1, l2, l3);
}

// ---------------- pure-bf16-plane split NT GEMM: C[M,N] = A[M,K] * B[N,K]^T ------
// A planes [M][K], B planes [N][K] bf16 hi/lo. 3 MFMAs per fragment pair.
// BM x 128 x 32 tile, 256 threads, 4 waves in 2x2 grid. m97-style staging:
// global_load_lds width=16 into no-pad [rows][32] LDS.
template<int BM>
__launch_bounds__(256, 2)
__global__ void gemm_bf16p(const ushort* __restrict__ Ah, const ushort* __restrict__ Al,
                           const ushort* __restrict__ Bh, const ushort* __restrict__ Bl,
                           float* __restrict__ C, int ldc,
                           int M, int N, int K) {
  constexpr int BN = 128, BK = 32;
  constexpr int RT = BM / 32;            // 16-row tiles per wave (2 wave-rows)
  constexpr int CT = 4;                  // 16-col tiles per wave (2 wave-cols)

  __shared__ ushort As[2][BM * BK];
  __shared__ ushort Bs[2][BN * BK];

  const int t    = threadIdx.x;
  const int bm   = blockIdx.y * BM;
  const int bn   = blockIdx.x * BN;
  const int wave = t >> 6, lane = t & 63;
  const int ml   = lane & 15, g4 = lane >> 4;
  const int wr   = wave & 1, wc = wave >> 1;
  const int r0   = wr * RT * 16, c0 = wc * CT * 16;

  f32x4 acc[RT][CT];
#pragma unroll
  for (int i = 0; i < RT; ++i)
#pragma unroll
    for (int j = 0; j < CT; ++j) acc[i][j] = (f32x4){0.f, 0.f, 0.f, 0.f};

  for (int k0 = 0; k0 < K; k0 += BK) {
    __syncthreads();   // previous iteration's LDS reads complete
    // ---- async staging: global -> LDS, 16B/lane ----
#pragma unroll
    for (int ii = 0; ii < BM / 64; ++ii) {
      int idx = t + ii * 256;            // quad index
      int row = idx >> 2, seg = idx & 3;
      size_t go = (size_t)(bm + row) * K + k0 + seg * 8;
      gl_lds16(Ah + go, &As[0][idx * 8]);
      gl_lds16(Al + go, &As[1][idx * 8]);
    }
#pragma unroll
    for (int ii = 0; ii < 2; ++ii) {     // BN=128
      int idx = t + ii * 256;
      int row = idx >> 2, seg = idx & 3;
      size_t go = (size_t)(bn + row) * K + k0 + seg * 8;   // may run past N into
      gl_lds16(Bh + go, &Bs[0][idx * 8]);                  // adjacent valid plane
      gl_lds16(Bl + go, &Bs[1][idx * 8]);
    }
    __syncthreads();   // compiler drains vmcnt(0) before barrier -> LDS ready

    // ---- fragments + MFMA (layouts verified in R3) ----
    short8 ah[RT], al[RT], bh[CT], bl[CT];
#pragma unroll
    for (int i = 0; i < RT; ++i) {
      int off = (r0 + i * 16 + ml) * BK + g4 * 8;
      ah[i] = *(const short8*)&As[0][off];
      al[i] = *(const short8*)&As[1][off];
    }
#pragma unroll
    for (int j = 0; j < CT; ++j) {
      int off = (c0 + j * 16 + ml) * BK + g4 * 8;
      bh[j] = *(const short8*)&Bs[0][off];
      bl[j] = *(const short8*)&Bs[1][off];
    }
#pragma unroll
    for (int i = 0; i < RT; ++i)
#pragma unroll
      for (int j = 0; j < CT; ++j) {
        acc[i][j] = __builtin_amdgcn_mfma_f32_16x16x32_bf16(ah[i], bh[j], acc[i][j], 0, 0, 0);
        acc[i][j] = __builtin_amdgcn_mfma_f32_16x16x32_bf16(ah[i], bl[j], acc[i][j], 0, 0, 0);
        acc[i][j] = __builtin_amdgcn_mfma_f32_16x16x32_bf16(al[i], bh[j], acc[i][j], 0, 0, 0);
      }
  }

  // ---- epilogue: C/D layout col=lane&15, row=(lane>>4)*4+reg ----
#pragma unroll
  for (int i = 0; i < RT; ++i)
#pragma unroll
    for (int j = 0; j < CT; ++j) {
      int col = bn + c0 + j * 16 + ml;
      if (col < N) {                       // N % 16 == 0 -> whole tile valid
        int rowb = bm + r0 + i * 16 + g4 * 4;
#pragma unroll
        for (int r = 0; r < 4; ++r)
          C[(size_t)(rowb + r) * ldc + col] = acc[i][j][r];
      }
    }
}

// ---------------- dt = softplus(raw_dt + dt_bias), one batch ----------------
__global__ void dt_softplus(const float* __restrict__ xbcdt,
                            const float* __restrict__ dt_bias,
                            float* __restrict__ dtb) {
  int idx = blockIdx.x * blockDim.x + threadIdx.x;
  if (idx >= SEQLEN * NHEADS) return;
  int h = idx & (NHEADS - 1);
  int l = idx >> 4;
  float x = xbcdt[(size_t)l * XBC_LD + DT_OFF + h] + dt_bias[h];
  dtb[idx] = (x > 20.f) ? x : log1pf(expf(x));
}

// ---------------- depthwise causal conv(4) + bias + SiLU, one batch ----------------
__global__ void conv_silu(const float* __restrict__ xbcdt,
                          const float* __restrict__ cw,
                          const float* __restrict__ cb,
                          float* __restrict__ xc) {
  int idx = blockIdx.x * blockDim.x + threadIdx.x;
  if (idx >= SEQLEN * CONV_DIM) return;
  int c = idx % CONV_DIM;
  int l = idx / CONV_DIM;
  const float w0 = cw[c * 4 + 0], w1 = cw[c * 4 + 1], w2 = cw[c * 4 + 2], w3 = cw[c * 4 + 3];
  const float* base = xbcdt + (size_t)l * XBC_LD + c;
  float acc = cb[c];
  if (l >= 3) acc = fmaf(w0, base[-(ptrdiff_t)3 * XBC_LD], acc);
  if (l >= 2) acc = fmaf(w1, base[-(ptrdiff_t)2 * XBC_LD], acc);
  if (l >= 1) acc = fmaf(w2, base[-(ptrdiff_t)1 * XBC_LD], acc);
  acc = fmaf(w3, base[0], acc);
  float sig = 1.f / (1.f + expf(-acc));
  xc[idx] = acc * sig;
}

// ---------------- chunked scan, pass A ----------------
__launch_bounds__(512, 1)
__global__ void scan_passA(const float* __restrict__ xc,
                           const float* __restrict__ dtb,
                           const float* __restrict__ A_log,
                           float* __restrict__ Sc, float* __restrict__ Pc) {
  const int blk = blockIdx.x;
  const int c   = blk & (NCHUNK - 1);
  const int h   = blk / NCHUNK;
  const int t   = threadIdx.x;
  const int p   = t >> 2;
  const int n0  = (t & 3) * 16;
  const float Ah = -expf(A_log[h]);

  float s[16];
#pragma unroll
  for (int i = 0; i < 16; ++i) s[i] = 0.f;
  float dprod = 1.f;

  __shared__ float xs[SCAN_T][HEADDIM];
  __shared__ float Bsh[SCAN_T][D_STATE];
  __shared__ float dts[SCAN_T];

  const int l0 = c * LCHUNK;
  for (int jt = 0; jt < LCHUNK; jt += SCAN_T) {
    __syncthreads();
    for (int idx = t; idx < SCAN_T * HEADDIM; idx += 512) {
      int r = idx >> 7, col = idx & 127;
      int l = l0 + jt + r;
      xs[r][col] = xc[(size_t)l * CONV_DIM + h * HEADDIM + col];
    }
    for (int idx = t; idx < SCAN_T * D_STATE; idx += 512) {
      int r = idx >> 6, col = idx & 63;
      int l = l0 + jt + r;
      Bsh[r][col] = xc[(size_t)l * CONV_DIM + D_INNER + col];
    }
    if (t < SCAN_T) {
      int l = l0 + jt + t;
      dts[t] = dtb[(size_t)l * NHEADS + h];
    }
    __syncthreads();
#pragma unroll 4
    for (int j = 0; j < SCAN_T; ++j) {
      float a  = expf(dts[j] * Ah);
      float xp = xs[j][p];
      dprod *= a;
#pragma unroll
      for (int i = 0; i < 16; ++i)
        s[i] = fmaf(a, s[i], Bsh[j][n0 + i] * xp);
    }
  }
  float* sp = Sc + (size_t)blk * (HEADDIM * D_STATE) + p * D_STATE + n0;
#pragma unroll
  for (int i = 0; i < 16; i += 4)
    *(float4*)(sp + i) = make_float4(s[i], s[i + 1], s[i + 2], s[i + 3]);
  if (t == 0) Pc[blk] = dprod;
}

// ---------------- pass B: exclusive prefix over chunks, in place, parallel -------
__global__ void scan_passB(float* __restrict__ Sc, const float* __restrict__ Pc) {
  const int h = blockIdx.x;
  const int e = blockIdx.y * 512 + threadIdx.x;   // 0..8191
  const size_t hb = (size_t)h * NCHUNK;
  float st = 0.f;
  for (int c = 0; c < NCHUNK; ++c) {
    size_t idx = (hb + c) * (HEADDIM * D_STATE) + e;
    float P = Pc[hb + c];
    float v = Sc[idx];
    Sc[idx] = st;
    st = fmaf(P, st, v);
  }
}

// ---------------- pass C: re-scan with true init, emit y (+ D*x) ----------------
__launch_bounds__(512, 1)
__global__ void scan_passC(const float* __restrict__ xc,
                           const float* __restrict__ dtb,
                           const float* __restrict__ A_log,
                           const float* __restrict__ Dp,
                           const float* __restrict__ Sinit,   // == Sc after passB
                           float* __restrict__ xbcdt) {
  const int blk = blockIdx.x;
  const int c   = blk & (NCHUNK - 1);
  const int h   = blk / NCHUNK;
  const int t   = threadIdx.x;
  const int p   = t >> 2;
  const int n0  = (t & 3) * 16;
  const float Ah = -expf(A_log[h]);
  const float Dh = Dp[h];

  float s[16];
  {
    const float* ip = Sinit + (size_t)blk * (HEADDIM * D_STATE) + p * D_STATE + n0;
#pragma unroll
    for (int i = 0; i < 16; i += 4) {
      float4 v = *(const float4*)(ip + i);
      s[i] = v.x; s[i + 1] = v.y; s[i + 2] = v.z; s[i + 3] = v.w;
    }
  }

  __shared__ float xs[SCAN_T][HEADDIM];
  __shared__ float Bsh[SCAN_T][D_STATE];
  __shared__ float Csh[SCAN_T][D_STATE];
  __shared__ float dts[SCAN_T];

  const int l0 = c * LCHUNK;
  for (int jt = 0; jt < LCHUNK; jt += SCAN_T) {
    __syncthreads();
    for (int idx = t; idx < SCAN_T * HEADDIM; idx += 512) {
      int r = idx >> 7, col = idx & 127;
      int l = l0 + jt + r;
      xs[r][col] = xc[(size_t)l * CONV_DIM + h * HEADDIM + col];
    }
    for (int idx = t; idx < SCAN_T * D_STATE * 2; idx += 512) {
      int r = idx / (D_STATE * 2), rem = idx % (D_STATE * 2);
      int l = l0 + jt + r;
      float v = xc[(size_t)l * CONV_DIM + D_INNER + rem];
      if (rem < D_STATE) Bsh[r][rem] = v;
      else               Csh[r][rem - D_STATE] = v;
    }
    if (t < SCAN_T) {
      int l = l0 + jt + t;
      dts[t] = dtb[(size_t)l * NHEADS + h];
    }
    __syncthreads();
    for (int j = 0; j < SCAN_T; ++j) {
      float a  = expf(dts[j] * Ah);
      float xp = xs[j][p];
      float part = 0.f;
#pragma unroll
      for (int i = 0; i < 16; ++i) {
        s[i] = fmaf(a, s[i], Bsh[j][n0 + i] * xp);
        part = fmaf(s[i], Csh[j][n0 + i], part);
      }
      part += __shfl_xor(part, 1);
      part += __shfl_xor(part, 2);
      if ((t & 3) == 0) {
        int l = l0 + jt + j;
        xbcdt[(size_t)l * XBC_LD + h * HEADDIM + p] = part + Dh * xp;
      }
    }
  }
}

// ------- RMSNorm + sigmoid(z) gate, emits gated y as bf16 hi/lo planes -------
__launch_bounds__(256)
__global__ void rmsnorm_gate_split(const float* __restrict__ xbcdt,
                                   const float* __restrict__ zbuf,
                                   const float* __restrict__ rms_w,
                                   ushort* __restrict__ yh, ushort* __restrict__ yl) {
  const int row = blockIdx.x;
  const int t   = threadIdx.x;
  const float* y = xbcdt + (size_t)row * XBC_LD;
  const float* z = zbuf  + (size_t)row * D_INNER;

  float4 a  = *(const float4*)(y + t * 8);
  float4 bq = *(const float4*)(y + t * 8 + 4);
  float ss = a.x * a.x + a.y * a.y + a.z * a.z + a.w * a.w +
             bq.x * bq.x + bq.y * bq.y + bq.z * bq.z + bq.w * bq.w;
#pragma unroll
  for (int off = 32; off > 0; off >>= 1) ss += __shfl_down(ss, off);
  __shared__ float red[4];
  if ((t & 63) == 0) red[t >> 6] = ss;
  __syncthreads();
  float tot = red[0] + red[1] + red[2] + red[3];
  float scale = rsqrtf(tot * (1.f / (float)D_INNER) + RMS_EPS);

  float vy[8] = {a.x, a.y, a.z, a.w, bq.x, bq.y, bq.z, bq.w};
  ushort hh[8], ll[8];
#pragma unroll
  for (int jj = 0; jj < 8; ++jj) {
    int col = t * 8 + jj;
    float zv = z[col];
    float g = 1.f / (1.f + expf(-zv));
    float v = vy[jj] * scale * rms_w[col] * g;
    hh[jj] = f2bf(v);
    ll[jj] = f2bf(v - bf2f(hh[jj]));
  }
  size_t o = (size_t)row * D_INNER + t * 8;
  *(ushort4*)(yh + o)     = make_ushort4(hh[0], hh[1], hh[2], hh[3]);
  *(ushort4*)(yh + o + 4) = make_ushort4(hh[4], hh[5], hh[6], hh[7]);
  *(ushort4*)(yl + o)     = make_ushort4(ll[0], ll[1], ll[2], ll[3]);
  *(ushort4*)(yl + o + 4) = make_ushort4(ll[4], ll[5], ll[6], ll[7]);
}

// ---------------- launch ----------------
// ws (floats): xbcdt 8,978,432 | xc 8,912,896 | dtb 65,536 | Pc 512 | Sc 4,194,304
//            | u planes 4,194,304 | w1 planes 4,341,760 | w2 planes 2,097,152
//            = 32,784,896 floats = 131.1 MB (125.1 MiB).
// y planes (16,777,216 ushorts) overlay [Sc .. u-planes end) — both dead by rmsnorm.
extern "C" void kernel_launch(void* const* d_in, const int* in_sizes, int n_in,
                              void* d_out, int out_size, void* d_ws, size_t ws_size,
                              hipStream_t stream) {
  const float* u         = (const float*)d_in[0];
  const float* in_proj_w = (const float*)d_in[1];
  const float* conv_w    = (const float*)d_in[2];
  const float* conv_b    = (const float*)d_in[3];
  const float* dt_bias   = (const float*)d_in[4];
  const float* A_log     = (const float*)d_in[5];
  const float* Dp        = (const float*)d_in[6];
  const float* rms_w     = (const float*)d_in[7];
  const float* out_w     = (const float*)d_in[8];
  float* out = (float*)d_out;

  float* ws    = (float*)d_ws;
  float* xbcdt = ws;                                           // [4096, 2192]
  float* xc    = xbcdt + (size_t)SEQLEN * XBC_LD;              // [4096, 2176]; z later
  float* dtb   = xc    + (size_t)SEQLEN * CONV_DIM;            // [4096, 16]
  float* Pc    = dtb   + (size_t)SEQLEN * NHEADS;              // [512]
  float* Sc    = Pc    + 512;                                  // [512, 8192]
  ushort* uh   = (ushort*)(Sc + (size_t)NHEADS * NCHUNK * HEADDIM * D_STATE);
  ushort* ul   = uh  + (size_t)SEQLEN * D_MODEL;               // u planes (per batch)
  ushort* w1h  = ul  + (size_t)SEQLEN * D_MODEL;
  ushort* w1l  = w1h + (size_t)D_IN_PROJ * D_MODEL;
  ushort* w2h  = w1l + (size_t)D_IN_PROJ * D_MODEL;
  ushort* w2l  = w2h + (size_t)D_MODEL * D_INNER;
  ushort* yh   = (ushort*)Sc;                                  // overlay Sc + u planes
  ushort* yl   = yh + (size_t)SEQLEN * D_INNER;
  float* zbuf  = xc;                                           // z after scan

  // weight splits (once per call)
  {
    int n4 = D_IN_PROJ * D_MODEL / 4;
    cvt_split<<<(n4 + 255) / 256, 256, 0, stream>>>(in_proj_w, w1h, w1l, n4);
    int m4 = D_MODEL * D_INNER / 4;
    cvt_split<<<(m4 + 255) / 256, 256, 0, stream>>>(out_w, w2h, w2l, m4);
  }

  for (int b = 0; b < BATCH; ++b) {
    const float* u_b  = u   + (size_t)b * SEQLEN * D_MODEL;
    float*      out_b = out + (size_t)b * SEQLEN * D_MODEL;

    // 0) split u_b -> bf16 planes
    {
      int n4 = SEQLEN * D_MODEL / 4;
      cvt_split<<<(n4 + 255) / 256, 256, 0, stream>>>(u_b, uh, ul, n4);
    }

    // 1) xBC|dt GEMM: xbcdt[4096,2192] = u * in_proj_w[2048:4240]^T
    {
      const ushort* bh = w1h + (size_t)D_INNER * D_MODEL;
      const ushort* bl = w1l + (size_t)D_INNER * D_MODEL;
      dim3 g((N_XBC + 127) / 128, SEQLEN / 128);
      gemm_bf16p<128><<<g, 256, 0, stream>>>(uh, ul, bh, bl,
                                             xbcdt, XBC_LD, SEQLEN, N_XBC, D_MODEL);
    }

    // 2) dt softplus
    dt_softplus<<<(SEQLEN * NHEADS + 255) / 256, 256, 0, stream>>>(xbcdt, dt_bias, dtb);

    // 3) depthwise conv + SiLU
    conv_silu<<<(SEQLEN * CONV_DIM + 255) / 256, 256, 0, stream>>>(xbcdt, conv_w, conv_b, xc);

    // 4-6) chunked scan (y lands in xbcdt cols [0,2048))
    scan_passA<<<NHEADS * NCHUNK, 512, 0, stream>>>(xc, dtb, A_log, Sc, Pc);
    scan_passB<<<dim3(NHEADS, (HEADDIM * D_STATE) / 512), 512, 0, stream>>>(Sc, Pc);
    scan_passC<<<NHEADS * NCHUNK, 512, 0, stream>>>(xc, dtb, A_log, Dp, Sc, xbcdt);

    // 5) deferred z GEMM into the (now dead) conv buffer; last use of u planes
    {
      dim3 g(D_INNER / 128, SEQLEN / 128);
      gemm_bf16p<128><<<g, 256, 0, stream>>>(uh, ul, w1h, w1l,
                                             zbuf, D_INNER, SEQLEN, D_INNER, D_MODEL);
    }

    // 7) RMSNorm + gate -> y bf16 planes (overlay Sc/u-planes, both dead now)
    rmsnorm_gate_split<<<SEQLEN, 256, 0, stream>>>(xbcdt, zbuf, rms_w, yh, yl);

    // 8) out GEMM: out_b[4096,1024] = y[4096,2048] * out_w^T
    {
      dim3 g(D_MODEL / 128, SEQLEN / 64);
      gemm_bf16p<64><<<g, 256, 0, stream>>>(yh, yl, w2h, w2l,
                                            out_b, D_MODEL, SEQLEN, D_MODEL, D_INNER);
    }
  }
}

// Round 5
// 756.389 us; speedup vs baseline: 2.5458x; 1.1325x over previous
//
#include <hip/hip_runtime.h>
#include <math.h>

// ---------------- problem constants ----------------
#define D_MODEL   1024
#define D_INNER   2048
#define D_STATE   64
#define HEADDIM   128
#define NHEADS    16
#define D_CONV    4
#define CONV_DIM  2176        // D_INNER + 2*D_STATE
#define BATCH     2
#define SEQLEN    4096
#define RMS_EPS   1e-5f

// xbcdt buffer: cols [0,2048)=x (y after scan), [2048,2112)=B, [2112,2176)=C, [2176,2192)=dt
#define XBC_LD    2192
#define DT_OFF    2176
#define N_XBC     2192
#define D_IN_PROJ 4240

#define LCHUNK    128
#define NCHUNK    (SEQLEN / LCHUNK)   // 32

typedef __attribute__((ext_vector_type(8))) short short8;
typedef __attribute__((ext_vector_type(4))) float f32x4;

__device__ __forceinline__ ushort f2bf(float f) {
  unsigned u = __float_as_uint(f);
  u += 0x7fff + ((u >> 16) & 1);          // RNE
  return (ushort)(u >> 16);
}
__device__ __forceinline__ float bf2f(ushort h) {
  return __uint_as_float(((unsigned)h) << 16);
}

// async global->LDS, 16B per lane (global_load_lds_dwordx4)
__device__ __forceinline__ void gl_lds16(const ushort* g, ushort* l) {
  __builtin_amdgcn_global_load_lds(
      (const __attribute__((address_space(1))) unsigned int*)g,
      (__attribute__((address_space(3))) unsigned int*)l, 16, 0, 0);
}

// ---------------- split fp32 -> bf16 hi/lo planes ----------------
__global__ void cvt_split(const float* __restrict__ w,
                          ushort* __restrict__ hi, ushort* __restrict__ lo, int n4) {
  int i = blockIdx.x * 256 + threadIdx.x;
  if (i >= n4) return;
  float4 v = ((const float4*)w)[i];
  ushort h0 = f2bf(v.x), h1 = f2bf(v.y), h2 = f2bf(v.z), h3 = f2bf(v.w);
  ushort l0 = f2bf(v.x - bf2f(h0)), l1 = f2bf(v.y - bf2f(h1));
  ushort l2 = f2bf(v.z - bf2f(h2)), l3 = f2bf(v.w - bf2f(h3));
  ((ushort4*)hi)[i] = make_ushort4(h0, h1, h2, h3);
  ((ushort4*)lo)[i] = make_ushort4(l0, l1, l2, l3);
}

// ---------------- pure-bf16-plane split NT GEMM (unchanged from R4) ------------
template<int BM>
__launch_bounds__(256, 2)
__global__ void gemm_bf16p(const ushort* __restrict__ Ah, const ushort* __restrict__ Al,
                           const ushort* __restrict__ Bh, const ushort* __restrict__ Bl,
                           float* __restrict__ C, int ldc,
                           int M, int N, int K) {
  constexpr int BN = 128, BK = 32;
  constexpr int RT = BM / 32;
  constexpr int CT = 4;

  __shared__ ushort As[2][BM * BK];
  __shared__ ushort Bs[2][BN * BK];

  const int t    = threadIdx.x;
  const int bm   = blockIdx.y * BM;
  const int bn   = blockIdx.x * BN;
  const int wave = t >> 6, lane = t & 63;
  const int ml   = lane & 15, g4 = lane >> 4;
  const int wr   = wave & 1, wc = wave >> 1;
  const int r0   = wr * RT * 16, c0 = wc * CT * 16;

  f32x4 acc[RT][CT];
#pragma unroll
  for (int i = 0; i < RT; ++i)
#pragma unroll
    for (int j = 0; j < CT; ++j) acc[i][j] = (f32x4){0.f, 0.f, 0.f, 0.f};

  for (int k0 = 0; k0 < K; k0 += BK) {
    __syncthreads();
#pragma unroll
    for (int ii = 0; ii < BM / 64; ++ii) {
      int idx = t + ii * 256;
      int row = idx >> 2, seg = idx & 3;
      size_t go = (size_t)(bm + row) * K + k0 + seg * 8;
      gl_lds16(Ah + go, &As[0][idx * 8]);
      gl_lds16(Al + go, &As[1][idx * 8]);
    }
#pragma unroll
    for (int ii = 0; ii < 2; ++ii) {
      int idx = t + ii * 256;
      int row = idx >> 2, seg = idx & 3;
      size_t go = (size_t)(bn + row) * K + k0 + seg * 8;
      gl_lds16(Bh + go, &Bs[0][idx * 8]);
      gl_lds16(Bl + go, &Bs[1][idx * 8]);
    }
    __syncthreads();

    short8 ah[RT], al[RT], bh[CT], bl[CT];
#pragma unroll
    for (int i = 0; i < RT; ++i) {
      int off = (r0 + i * 16 + ml) * BK + g4 * 8;
      ah[i] = *(const short8*)&As[0][off];
      al[i] = *(const short8*)&As[1][off];
    }
#pragma unroll
    for (int j = 0; j < CT; ++j) {
      int off = (c0 + j * 16 + ml) * BK + g4 * 8;
      bh[j] = *(const short8*)&Bs[0][off];
      bl[j] = *(const short8*)&Bs[1][off];
    }
#pragma unroll
    for (int i = 0; i < RT; ++i)
#pragma unroll
      for (int j = 0; j < CT; ++j) {
        acc[i][j] = __builtin_amdgcn_mfma_f32_16x16x32_bf16(ah[i], bh[j], acc[i][j], 0, 0, 0);
        acc[i][j] = __builtin_amdgcn_mfma_f32_16x16x32_bf16(ah[i], bl[j], acc[i][j], 0, 0, 0);
        acc[i][j] = __builtin_amdgcn_mfma_f32_16x16x32_bf16(al[i], bh[j], acc[i][j], 0, 0, 0);
      }
  }

#pragma unroll
  for (int i = 0; i < RT; ++i)
#pragma unroll
    for (int j = 0; j < CT; ++j) {
      int col = bn + c0 + j * 16 + ml;
      if (col < N) {
        int rowb = bm + r0 + i * 16 + g4 * 4;
#pragma unroll
        for (int r = 0; r < 4; ++r)
          C[(size_t)(rowb + r) * ldc + col] = acc[i][j][r];
      }
    }
}

// ---------------- dt = softplus(raw_dt + dt_bias), one batch ----------------
__global__ void dt_softplus(const float* __restrict__ xbcdt,
                            const float* __restrict__ dt_bias,
                            float* __restrict__ dtb) {
  int idx = blockIdx.x * blockDim.x + threadIdx.x;
  if (idx >= SEQLEN * NHEADS) return;
  int h = idx & (NHEADS - 1);
  int l = idx >> 4;
  float x = xbcdt[(size_t)l * XBC_LD + DT_OFF + h] + dt_bias[h];
  dtb[idx] = (x > 20.f) ? x : log1pf(expf(x));
}

// ---------------- depthwise causal conv(4) + bias + SiLU, one batch ----------------
__global__ void conv_silu(const float* __restrict__ xbcdt,
                          const float* __restrict__ cw,
                          const float* __restrict__ cb,
                          float* __restrict__ xc) {
  int idx = blockIdx.x * blockDim.x + threadIdx.x;
  if (idx >= SEQLEN * CONV_DIM) return;
  int c = idx % CONV_DIM;
  int l = idx / CONV_DIM;
  const float w0 = cw[c * 4 + 0], w1 = cw[c * 4 + 1], w2 = cw[c * 4 + 2], w3 = cw[c * 4 + 3];
  const float* base = xbcdt + (size_t)l * XBC_LD + c;
  float acc = cb[c];
  if (l >= 3) acc = fmaf(w0, base[-(ptrdiff_t)3 * XBC_LD], acc);
  if (l >= 2) acc = fmaf(w1, base[-(ptrdiff_t)2 * XBC_LD], acc);
  if (l >= 1) acc = fmaf(w2, base[-(ptrdiff_t)1 * XBC_LD], acc);
  acc = fmaf(w3, base[0], acc);
  float sig = 1.f / (1.f + expf(-acc));
  xc[idx] = acc * sig;
}

// =================== SSD chunked scan on MFMA ===================
// Block = (h, c). Within chunk (Lc=128):
//   passA: S_c[p][n] = sum_t w_t * X[t][p] * B[t][n],  w_t = exp(cum[Lc-1]-cum[t])
//   passC: Y[t][p]   = sum_{s<=t} exp(cum[t]-cum[s]) (C_t . B_s) X[s][p]
//                    + exp(cum[t]) * (C_t . S_init[p][:])  + D_h * X[t][p]
// All matmuls split-bf16 (hi/lo, 3 MFMAs). cum = inclusive prefix of dt*A.

// ---------------- pass A (SSD): per-chunk local state via MFMA ----------------
__launch_bounds__(256, 2)
__global__ void passA_ssd(const float* __restrict__ xc,
                          const float* __restrict__ dtb,
                          const float* __restrict__ A_log,
                          float* __restrict__ Sc, float* __restrict__ Pc) {
  const int blk = blockIdx.x;
  const int c   = blk & (NCHUNK - 1);
  const int h   = blk >> 5;
  const int l0  = c * LCHUNK;
  const int t   = threadIdx.x;
  const int wave = t >> 6, lane = t & 63;
  const int ml = lane & 15, g4 = lane >> 4;
  const float Ah = -expf(A_log[h]);

  __shared__ float cum[LCHUNK];
  __shared__ ushort Xt[2][LCHUNK * 40];   // X^T slab: [p][s], stride 40
  __shared__ ushort Bt[2][D_STATE * 40];  // (diag(w)B)^T slab: [n][s]

  // inclusive prefix of dt*Ah
  if (t < LCHUNK) cum[t] = dtb[(size_t)(l0 + t) * NHEADS + h] * Ah;
  __syncthreads();
  for (int off = 1; off < LCHUNK; off <<= 1) {
    float v = (t < LCHUNK && t >= off) ? cum[t - off] : 0.f;
    __syncthreads();
    if (t < LCHUNK) cum[t] += v;
    __syncthreads();
  }
  const float cend = cum[LCHUNK - 1];

  f32x4 acc[2][4];                       // wave: 2 p-tiles x 4 n-tiles
#pragma unroll
  for (int i = 0; i < 2; ++i)
#pragma unroll
    for (int j = 0; j < 4; ++j) acc[i][j] = (f32x4){0.f, 0.f, 0.f, 0.f};
  const int p0 = wave * 32;

  for (int slab = 0; slab < 4; ++slab) {
    __syncthreads();
    // stage X^T slab (plain transpose)
    for (int i = 0; i < 4; ++i) {
      int q = t + i * 256;                    // 1024 float4
      int s = q >> 5, p4 = (q & 31) * 4;
      const float* src = xc + (size_t)(l0 + slab * 32 + s) * CONV_DIM + h * HEADDIM + p4;
      float4 v = *(const float4*)src;
      float vv[4] = {v.x, v.y, v.z, v.w};
#pragma unroll
      for (int j = 0; j < 4; ++j) {
        ushort hh = f2bf(vv[j]);
        Xt[0][(p4 + j) * 40 + s] = hh;
        Xt[1][(p4 + j) * 40 + s] = f2bf(vv[j] - bf2f(hh));
      }
    }
    // stage (diag(w) B)^T slab
    for (int i = 0; i < 2; ++i) {
      int q = t + i * 256;                    // 512 float4
      int s = q >> 4, n4 = (q & 15) * 4;
      float w = __expf(cend - cum[slab * 32 + s]);
      const float* src = xc + (size_t)(l0 + slab * 32 + s) * CONV_DIM + D_INNER + n4;
      float4 v = *(const float4*)src;
      float vv[4] = {v.x * w, v.y * w, v.z * w, v.w * w};
#pragma unroll
      for (int j = 0; j < 4; ++j) {
        ushort hh = f2bf(vv[j]);
        Bt[0][(n4 + j) * 40 + s] = hh;
        Bt[1][(n4 + j) * 40 + s] = f2bf(vv[j] - bf2f(hh));
      }
    }
    __syncthreads();

    short8 xa_h[2], xa_l[2];
#pragma unroll
    for (int pi = 0; pi < 2; ++pi) {
      int off = (p0 + pi * 16 + ml) * 40 + g4 * 8;
      xa_h[pi] = *(const short8*)&Xt[0][off];
      xa_l[pi] = *(const short8*)&Xt[1][off];
    }
#pragma unroll
    for (int ni = 0; ni < 4; ++ni) {
      int off = (ni * 16 + ml) * 40 + g4 * 8;
      short8 bh = *(const short8*)&Bt[0][off];
      short8 bl = *(const short8*)&Bt[1][off];
#pragma unroll
      for (int pi = 0; pi < 2; ++pi) {
        acc[pi][ni] = __builtin_amdgcn_mfma_f32_16x16x32_bf16(xa_h[pi], bh, acc[pi][ni], 0, 0, 0);
        acc[pi][ni] = __builtin_amdgcn_mfma_f32_16x16x32_bf16(xa_h[pi], bl, acc[pi][ni], 0, 0, 0);
        acc[pi][ni] = __builtin_amdgcn_mfma_f32_16x16x32_bf16(xa_l[pi], bh, acc[pi][ni], 0, 0, 0);
      }
    }
  }

  float* S = Sc + (size_t)blk * (HEADDIM * D_STATE);
#pragma unroll
  for (int pi = 0; pi < 2; ++pi)
#pragma unroll
    for (int ni = 0; ni < 4; ++ni) {
      int n = ni * 16 + ml;
#pragma unroll
      for (int r = 0; r < 4; ++r) {
        int p = p0 + pi * 16 + g4 * 4 + r;
        S[(size_t)p * D_STATE + n] = acc[pi][ni][r];
      }
    }
  if (t == 0) Pc[blk] = __expf(cend);
}

// ---------------- pass B: exclusive prefix over chunks (unchanged) -------
__global__ void scan_passB(float* __restrict__ Sc, const float* __restrict__ Pc) {
  const int h = blockIdx.x;
  const int e = blockIdx.y * 512 + threadIdx.x;
  const size_t hb = (size_t)h * NCHUNK;
  float st = 0.f;
  for (int c = 0; c < NCHUNK; ++c) {
    size_t idx = (hb + c) * (HEADDIM * D_STATE) + e;
    float P = Pc[hb + c];
    float v = Sc[idx];
    Sc[idx] = st;
    st = fmaf(P, st, v);
  }
}

// ---------------- pass C (SSD): intra-chunk attention + inter-chunk term ----------
__launch_bounds__(256, 2)
__global__ void passC_ssd(const float* __restrict__ xc,
                          const float* __restrict__ dtb,
                          const float* __restrict__ A_log,
                          const float* __restrict__ Dp,
                          const float* __restrict__ Sc,     // exclusive prefix states
                          float* __restrict__ xbcdt) {
  const int blk = blockIdx.x;
  const int c   = blk & (NCHUNK - 1);
  const int h   = blk >> 5;
  const int l0  = c * LCHUNK;
  const int t   = threadIdx.x;
  const int wave = t >> 6, lane = t & 63;
  const int ml = lane & 15, g4 = lane >> 4;
  const float Ah = -expf(A_log[h]);
  const float Dh = Dp[h];

  __shared__ float cum[LCHUNK];
  __shared__ ushort Csl[2][2][LCHUNK * 32];  // C k-slabs [n-slab][hi/lo][t][32]
  __shared__ ushort Bsl[2][2][32 * 32];      // B s-slab  [n-slab][hi/lo][s][32]
  __shared__ ushort Msl[2][LCHUNK * 32];     // masked-decay matrix slab [t][32]
  __shared__ ushort Xt[2][LCHUNK * 40];      // X^T (or S_init) slab [p][k], stride 40

  if (t < LCHUNK) cum[t] = dtb[(size_t)(l0 + t) * NHEADS + h] * Ah;
  __syncthreads();
  for (int off = 1; off < LCHUNK; off <<= 1) {
    float v = (t < LCHUNK && t >= off) ? cum[t - off] : 0.f;
    __syncthreads();
    if (t < LCHUNK) cum[t] += v;
    __syncthreads();
  }

  // stage C (resident): 128 rows x 64 cols -> two 32-wide k-slabs, split hi/lo
  {
    int row = t >> 1, half = t & 1;
    const float* src = xc + (size_t)(l0 + row) * CONV_DIM + D_INNER + D_STATE + half * 32;
    ushort* dh = &Csl[half][0][row * 32];
    ushort* dl = &Csl[half][1][row * 32];
#pragma unroll
    for (int j = 0; j < 32; j += 4) {
      float4 v = *(const float4*)(src + j);
      ushort h0 = f2bf(v.x), h1 = f2bf(v.y), h2 = f2bf(v.z), h3 = f2bf(v.w);
      *(ushort4*)(dh + j) = make_ushort4(h0, h1, h2, h3);
      *(ushort4*)(dl + j) = make_ushort4(f2bf(v.x - bf2f(h0)), f2bf(v.y - bf2f(h1)),
                                         f2bf(v.z - bf2f(h2)), f2bf(v.w - bf2f(h3)));
    }
  }

  f32x4 accY[2][8];                          // wave: 2 t-tiles x 8 p-tiles
#pragma unroll
  for (int i = 0; i < 2; ++i)
#pragma unroll
    for (int j = 0; j < 8; ++j) accY[i][j] = (f32x4){0.f, 0.f, 0.f, 0.f};
  const int t0 = wave * 32;

  // ---- intra-chunk: 4 s-slabs ----
  for (int slab = 0; slab < 4; ++slab) {
    __syncthreads();
    // stage B s-slab: 32 rows x 64 cols -> two n-slabs
    for (int i = 0; i < 2; ++i) {
      int q = t + i * 256;
      int s = q >> 4, c4 = (q & 15) * 4;
      const float* src = xc + (size_t)(l0 + slab * 32 + s) * CONV_DIM + D_INNER + c4;
      float4 v = *(const float4*)src;
      int ks = c4 >> 5, jj = c4 & 31;
      ushort h0 = f2bf(v.x), h1 = f2bf(v.y), h2 = f2bf(v.z), h3 = f2bf(v.w);
      *(ushort4*)&Bsl[ks][0][s * 32 + jj] = make_ushort4(h0, h1, h2, h3);
      *(ushort4*)&Bsl[ks][1][s * 32 + jj] =
          make_ushort4(f2bf(v.x - bf2f(h0)), f2bf(v.y - bf2f(h1)),
                       f2bf(v.z - bf2f(h2)), f2bf(v.w - bf2f(h3)));
    }
    // stage X^T slab (transpose)
    for (int i = 0; i < 4; ++i) {
      int q = t + i * 256;
      int s = q >> 5, p4 = (q & 31) * 4;
      const float* src = xc + (size_t)(l0 + slab * 32 + s) * CONV_DIM + h * HEADDIM + p4;
      float4 v = *(const float4*)src;
      float vv[4] = {v.x, v.y, v.z, v.w};
#pragma unroll
      for (int j = 0; j < 4; ++j) {
        ushort hh = f2bf(vv[j]);
        Xt[0][(p4 + j) * 40 + s] = hh;
        Xt[1][(p4 + j) * 40 + s] = f2bf(vv[j] - bf2f(hh));
      }
    }
    __syncthreads();

    // phase 1: G = C . B^T for this slab (K = 64, two 32-ksteps)
    f32x4 g[2][2];
#pragma unroll
    for (int i = 0; i < 2; ++i)
#pragma unroll
      for (int j = 0; j < 2; ++j) g[i][j] = (f32x4){0.f, 0.f, 0.f, 0.f};
#pragma unroll
    for (int ks = 0; ks < 2; ++ks) {
      short8 ca_h[2], ca_l[2];
#pragma unroll
      for (int ti = 0; ti < 2; ++ti) {
        int off = (t0 + ti * 16 + ml) * 32 + g4 * 8;
        ca_h[ti] = *(const short8*)&Csl[ks][0][off];
        ca_l[ti] = *(const short8*)&Csl[ks][1][off];
      }
#pragma unroll
      for (int si = 0; si < 2; ++si) {
        int off = (si * 16 + ml) * 32 + g4 * 8;
        short8 bh = *(const short8*)&Bsl[ks][0][off];
        short8 bl = *(const short8*)&Bsl[ks][1][off];
#pragma unroll
        for (int ti = 0; ti < 2; ++ti) {
          g[ti][si] = __builtin_amdgcn_mfma_f32_16x16x32_bf16(ca_h[ti], bh, g[ti][si], 0, 0, 0);
          g[ti][si] = __builtin_amdgcn_mfma_f32_16x16x32_bf16(ca_h[ti], bl, g[ti][si], 0, 0, 0);
          g[ti][si] = __builtin_amdgcn_mfma_f32_16x16x32_bf16(ca_l[ti], bh, g[ti][si], 0, 0, 0);
        }
      }
    }
    // mask + decay + split -> Msl
#pragma unroll
    for (int ti = 0; ti < 2; ++ti)
#pragma unroll
      for (int si = 0; si < 2; ++si) {
        int sl = si * 16 + ml;
        int sg = slab * 32 + sl;
#pragma unroll
        for (int r = 0; r < 4; ++r) {
          int tg = t0 + ti * 16 + g4 * 4 + r;
          float coeff = (sg <= tg) ? __expf(cum[tg] - cum[sg]) : 0.f;
          float val = g[ti][si][r] * coeff;
          ushort hh = f2bf(val);
          Msl[0][tg * 32 + sl] = hh;
          Msl[1][tg * 32 + sl] = f2bf(val - bf2f(hh));
        }
      }
    __syncthreads();
    // phase 2: Y += M . X^T
    {
      short8 ma_h[2], ma_l[2];
#pragma unroll
      for (int ti = 0; ti < 2; ++ti) {
        int off = (t0 + ti * 16 + ml) * 32 + g4 * 8;
        ma_h[ti] = *(const short8*)&Msl[0][off];
        ma_l[ti] = *(const short8*)&Msl[1][off];
      }
#pragma unroll
      for (int pi = 0; pi < 8; ++pi) {
        int off = (pi * 16 + ml) * 40 + g4 * 8;
        short8 xh = *(const short8*)&Xt[0][off];
        short8 xl = *(const short8*)&Xt[1][off];
#pragma unroll
        for (int ti = 0; ti < 2; ++ti) {
          accY[ti][pi] = __builtin_amdgcn_mfma_f32_16x16x32_bf16(ma_h[ti], xh, accY[ti][pi], 0, 0, 0);
          accY[ti][pi] = __builtin_amdgcn_mfma_f32_16x16x32_bf16(ma_h[ti], xl, accY[ti][pi], 0, 0, 0);
          accY[ti][pi] = __builtin_amdgcn_mfma_f32_16x16x32_bf16(ma_l[ti], xh, accY[ti][pi], 0, 0, 0);
        }
      }
    }
  }

  // ---- inter-chunk: Y += diag(exp(cum)) C . S_init  (K = 64, two 32-slabs) ----
  const float* S = Sc + (size_t)blk * (HEADDIM * D_STATE);
  for (int ns = 0; ns < 2; ++ns) {
    __syncthreads();
    // stage S_init slab: [p][ns*32 + j] fp32 -> Xt planes
    for (int i = 0; i < 4; ++i) {
      int q = t + i * 256;
      int p = q >> 3, j4 = (q & 7) * 4;
      float4 v = *(const float4*)(S + (size_t)p * D_STATE + ns * 32 + j4);
      float vv[4] = {v.x, v.y, v.z, v.w};
      ushort hh0 = f2bf(vv[0]), hh1 = f2bf(vv[1]), hh2 = f2bf(vv[2]), hh3 = f2bf(vv[3]);
      *(ushort4*)&Xt[0][p * 40 + j4] = make_ushort4(hh0, hh1, hh2, hh3);
      *(ushort4*)&Xt[1][p * 40 + j4] =
          make_ushort4(f2bf(vv[0] - bf2f(hh0)), f2bf(vv[1] - bf2f(hh1)),
                       f2bf(vv[2] - bf2f(hh2)), f2bf(vv[3] - bf2f(hh3)));
    }
    // build M[t][j] = exp(cum[t]) * C[t][ns*32+j]
    {
      int row = t >> 1, j0 = (t & 1) * 16;
      float e = __expf(cum[row]);
#pragma unroll
      for (int j = 0; j < 16; ++j) {
        int idx = row * 32 + j0 + j;
        float cv = bf2f(Csl[ns][0][idx]) + bf2f(Csl[ns][1][idx]);
        float val = cv * e;
        ushort hh = f2bf(val);
        Msl[0][idx] = hh;
        Msl[1][idx] = f2bf(val - bf2f(hh));
      }
    }
    __syncthreads();
    {
      short8 ma_h[2], ma_l[2];
#pragma unroll
      for (int ti = 0; ti < 2; ++ti) {
        int off = (t0 + ti * 16 + ml) * 32 + g4 * 8;
        ma_h[ti] = *(const short8*)&Msl[0][off];
        ma_l[ti] = *(const short8*)&Msl[1][off];
      }
#pragma unroll
      for (int pi = 0; pi < 8; ++pi) {
        int off = (pi * 16 + ml) * 40 + g4 * 8;
        short8 xh = *(const short8*)&Xt[0][off];
        short8 xl = *(const short8*)&Xt[1][off];
#pragma unroll
        for (int ti = 0; ti < 2; ++ti) {
          accY[ti][pi] = __builtin_amdgcn_mfma_f32_16x16x32_bf16(ma_h[ti], xh, accY[ti][pi], 0, 0, 0);
          accY[ti][pi] = __builtin_amdgcn_mfma_f32_16x16x32_bf16(ma_h[ti], xl, accY[ti][pi], 0, 0, 0);
          accY[ti][pi] = __builtin_amdgcn_mfma_f32_16x16x32_bf16(ma_l[ti], xh, accY[ti][pi], 0, 0, 0);
        }
      }
    }
  }

  // ---- epilogue: y = accY + D*x into xbcdt cols [0,2048) ----
#pragma unroll
  for (int ti = 0; ti < 2; ++ti)
#pragma unroll
    for (int pi = 0; pi < 8; ++pi) {
      int p = pi * 16 + ml;
#pragma unroll
      for (int r = 0; r < 4; ++r) {
        int l = l0 + t0 + ti * 16 + g4 * 4 + r;
        float x = xc[(size_t)l * CONV_DIM + h * HEADDIM + p];
        xbcdt[(size_t)l * XBC_LD + h * HEADDIM + p] = accY[ti][pi][r] + Dh * x;
      }
    }
}

// ------- RMSNorm + sigmoid(z) gate, emits gated y as bf16 hi/lo planes -------
__launch_bounds__(256)
__global__ void rmsnorm_gate_split(const float* __restrict__ xbcdt,
                                   const float* __restrict__ zbuf,
                                   const float* __restrict__ rms_w,
                                   ushort* __restrict__ yh, ushort* __restrict__ yl) {
  const int row = blockIdx.x;
  const int t   = threadIdx.x;
  const float* y = xbcdt + (size_t)row * XBC_LD;
  const float* z = zbuf  + (size_t)row * D_INNER;

  float4 a  = *(const float4*)(y + t * 8);
  float4 bq = *(const float4*)(y + t * 8 + 4);
  float ss = a.x * a.x + a.y * a.y + a.z * a.z + a.w * a.w +
             bq.x * bq.x + bq.y * bq.y + bq.z * bq.z + bq.w * bq.w;
#pragma unroll
  for (int off = 32; off > 0; off >>= 1) ss += __shfl_down(ss, off);
  __shared__ float red[4];
  if ((t & 63) == 0) red[t >> 6] = ss;
  __syncthreads();
  float tot = red[0] + red[1] + red[2] + red[3];
  float scale = rsqrtf(tot * (1.f / (float)D_INNER) + RMS_EPS);

  float vy[8] = {a.x, a.y, a.z, a.w, bq.x, bq.y, bq.z, bq.w};
  ushort hh[8], ll[8];
#pragma unroll
  for (int jj = 0; jj < 8; ++jj) {
    int col = t * 8 + jj;
    float zv = z[col];
    float g = 1.f / (1.f + expf(-zv));
    float v = vy[jj] * scale * rms_w[col] * g;
    hh[jj] = f2bf(v);
    ll[jj] = f2bf(v - bf2f(hh[jj]));
  }
  size_t o = (size_t)row * D_INNER + t * 8;
  *(ushort4*)(yh + o)     = make_ushort4(hh[0], hh[1], hh[2], hh[3]);
  *(ushort4*)(yh + o + 4) = make_ushort4(hh[4], hh[5], hh[6], hh[7]);
  *(ushort4*)(yl + o)     = make_ushort4(ll[0], ll[1], ll[2], ll[3]);
  *(ushort4*)(yl + o + 4) = make_ushort4(ll[4], ll[5], ll[6], ll[7]);
}

// ---------------- launch ----------------
// ws (floats): xbcdt 8,978,432 | xc 8,912,896 | dtb 65,536 | Pc 512 | Sc 4,194,304
//            | u planes 4,194,304 | w1 planes 4,341,760 | w2 planes 2,097,152
//            = 32,784,896 floats = 131.1 MB (same as R4's passing layout).
// y planes overlay [Sc .. u-planes) — dead by rmsnorm time. zbuf aliases xc.
extern "C" void kernel_launch(void* const* d_in, const int* in_sizes, int n_in,
                              void* d_out, int out_size, void* d_ws, size_t ws_size,
                              hipStream_t stream) {
  const float* u         = (const float*)d_in[0];
  const float* in_proj_w = (const float*)d_in[1];
  const float* conv_w    = (const float*)d_in[2];
  const float* conv_b    = (const float*)d_in[3];
  const float* dt_bias   = (const float*)d_in[4];
  const float* A_log     = (const float*)d_in[5];
  const float* Dp        = (const float*)d_in[6];
  const float* rms_w     = (const float*)d_in[7];
  const float* out_w     = (const float*)d_in[8];
  float* out = (float*)d_out;

  float* ws    = (float*)d_ws;
  float* xbcdt = ws;                                           // [4096, 2192]
  float* xc    = xbcdt + (size_t)SEQLEN * XBC_LD;              // [4096, 2176]; z later
  float* dtb   = xc    + (size_t)SEQLEN * CONV_DIM;            // [4096, 16]
  float* Pc    = dtb   + (size_t)SEQLEN * NHEADS;              // [512]
  float* Sc    = Pc    + 512;                                  // [512, 8192]
  ushort* uh   = (ushort*)(Sc + (size_t)NHEADS * NCHUNK * HEADDIM * D_STATE);
  ushort* ul   = uh  + (size_t)SEQLEN * D_MODEL;
  ushort* w1h  = ul  + (size_t)SEQLEN * D_MODEL;
  ushort* w1l  = w1h + (size_t)D_IN_PROJ * D_MODEL;
  ushort* w2h  = w1l + (size_t)D_IN_PROJ * D_MODEL;
  ushort* w2l  = w2h + (size_t)D_MODEL * D_INNER;
  ushort* yh   = (ushort*)Sc;                                  // overlay Sc + u planes
  ushort* yl   = yh + (size_t)SEQLEN * D_INNER;
  float* zbuf  = xc;                                           // z after scan

  // weight splits (once per call)
  {
    int n4 = D_IN_PROJ * D_MODEL / 4;
    cvt_split<<<(n4 + 255) / 256, 256, 0, stream>>>(in_proj_w, w1h, w1l, n4);
    int m4 = D_MODEL * D_INNER / 4;
    cvt_split<<<(m4 + 255) / 256, 256, 0, stream>>>(out_w, w2h, w2l, m4);
  }

  for (int b = 0; b < BATCH; ++b) {
    const float* u_b  = u   + (size_t)b * SEQLEN * D_MODEL;
    float*      out_b = out + (size_t)b * SEQLEN * D_MODEL;

    // 0) split u_b -> bf16 planes
    {
      int n4 = SEQLEN * D_MODEL / 4;
      cvt_split<<<(n4 + 255) / 256, 256, 0, stream>>>(u_b, uh, ul, n4);
    }

    // 1) xBC|dt GEMM
    {
      const ushort* bh = w1h + (size_t)D_INNER * D_MODEL;
      const ushort* bl = w1l + (size_t)D_INNER * D_MODEL;
      dim3 g((N_XBC + 127) / 128, SEQLEN / 128);
      gemm_bf16p<128><<<g, 256, 0, stream>>>(uh, ul, bh, bl,
                                             xbcdt, XBC_LD, SEQLEN, N_XBC, D_MODEL);
    }

    // 2) dt softplus
    dt_softplus<<<(SEQLEN * NHEADS + 255) / 256, 256, 0, stream>>>(xbcdt, dt_bias, dtb);

    // 3) depthwise conv + SiLU
    conv_silu<<<(SEQLEN * CONV_DIM + 255) / 256, 256, 0, stream>>>(xbcdt, conv_w, conv_b, xc);

    // 4-6) SSD chunked scan on MFMA
    passA_ssd<<<NHEADS * NCHUNK, 256, 0, stream>>>(xc, dtb, A_log, Sc, Pc);
    scan_passB<<<dim3(NHEADS, (HEADDIM * D_STATE) / 512), 512, 0, stream>>>(Sc, Pc);
    passC_ssd<<<NHEADS * NCHUNK, 256, 0, stream>>>(xc, dtb, A_log, Dp, Sc, xbcdt);

    // 5) deferred z GEMM into the (now dead) conv buffer; last use of u planes
    {
      dim3 g(D_INNER / 128, SEQLEN / 128);
      gemm_bf16p<128><<<g, 256, 0, stream>>>(uh, ul, w1h, w1l,
                                             zbuf, D_INNER, SEQLEN, D_INNER, D_MODEL);
    }

    // 7) RMSNorm + gate -> y bf16 planes (overlay Sc/u-planes, both dead now)
    rmsnorm_gate_split<<<SEQLEN, 256, 0, stream>>>(xbcdt, zbuf, rms_w, yh, yl);

    // 8) out GEMM
    {
      dim3 g(D_MODEL / 128, SEQLEN / 64);
      gemm_bf16p<64><<<g, 256, 0, stream>>>(yh, yl, w2h, w2l,
                                            out_b, D_MODEL, SEQLEN, D_MODEL, D_INNER);
    }
  }
}

// Round 6
// 749.801 us; speedup vs baseline: 2.5681x; 1.0088x over previous
//
#include <hip/hip_runtime.h>
#include <math.h>

// ---------------- problem constants ----------------
#define D_MODEL   1024
#define D_INNER   2048
#define D_STATE   64
#define HEADDIM   128
#define NHEADS    16
#define D_CONV    4
#define CONV_DIM  2176        // D_INNER + 2*D_STATE
#define BATCH     2
#define SEQLEN    4096
#define RMS_EPS   1e-5f

// xbcdt buffer: cols [0,2048)=x (y after scan), [2048,2112)=B, [2112,2176)=C, [2176,2192)=dt
#define XBC_LD    2192
#define DT_OFF    2176
#define N_XBC     2192
#define D_IN_PROJ 4240

#define LCHUNK    128
#define NCHUNK    (SEQLEN / LCHUNK)   // 32

typedef __attribute__((ext_vector_type(8))) short short8;
typedef __attribute__((ext_vector_type(4))) float f32x4;

__device__ __forceinline__ ushort f2bf(float f) {
  unsigned u = __float_as_uint(f);
  u += 0x7fff + ((u >> 16) & 1);          // RNE
  return (ushort)(u >> 16);
}
__device__ __forceinline__ float bf2f(ushort h) {
  return __uint_as_float(((unsigned)h) << 16);
}

// async global->LDS, 16B per lane (global_load_lds_dwordx4)
__device__ __forceinline__ void gl_lds16(const ushort* g, ushort* l) {
  __builtin_amdgcn_global_load_lds(
      (const __attribute__((address_space(1))) unsigned int*)g,
      (__attribute__((address_space(3))) unsigned int*)l, 16, 0, 0);
}

// ---------------- split fp32 -> bf16 hi/lo planes ----------------
__global__ void cvt_split(const float* __restrict__ w,
                          ushort* __restrict__ hi, ushort* __restrict__ lo, int n4) {
  int i = blockIdx.x * 256 + threadIdx.x;
  if (i >= n4) return;
  float4 v = ((const float4*)w)[i];
  ushort h0 = f2bf(v.x), h1 = f2bf(v.y), h2 = f2bf(v.z), h3 = f2bf(v.w);
  ushort l0 = f2bf(v.x - bf2f(h0)), l1 = f2bf(v.y - bf2f(h1));
  ushort l2 = f2bf(v.z - bf2f(h2)), l3 = f2bf(v.w - bf2f(h3));
  ((ushort4*)hi)[i] = make_ushort4(h0, h1, h2, h3);
  ((ushort4*)lo)[i] = make_ushort4(l0, l1, l2, l3);
}

// ---------------- pure-bf16-plane split NT GEMM: C[M,N] = A[M,K] * B[N,K]^T ------
// A planes [M][ldab], B planes [N][ldab]. grid.z = split-K slice index; each slice
// covers Kslice of K starting at z*Kslice, writing to partial plane C + z*M*ldc.
template<int BM>
__launch_bounds__(256, 2)
__global__ void gemm_bf16p(const ushort* __restrict__ Ah, const ushort* __restrict__ Al,
                           const ushort* __restrict__ Bh, const ushort* __restrict__ Bl,
                           float* __restrict__ C, int ldc,
                           int M, int N, int ldab, int Kslice) {
  constexpr int BN = 128, BK = 32;
  constexpr int RT = BM / 32;
  constexpr int CT = 4;

  __shared__ ushort As[2][BM * BK];
  __shared__ ushort Bs[2][BN * BK];

  const int t    = threadIdx.x;
  const int bm   = blockIdx.y * BM;
  const int bn   = blockIdx.x * BN;
  const int kz   = blockIdx.z;
  const int kb   = kz * Kslice;
  C += (size_t)kz * M * ldc;               // partial plane for split-K
  const int wave = t >> 6, lane = t & 63;
  const int ml   = lane & 15, g4 = lane >> 4;
  const int wr   = wave & 1, wc = wave >> 1;
  const int r0   = wr * RT * 16, c0 = wc * CT * 16;

  f32x4 acc[RT][CT];
#pragma unroll
  for (int i = 0; i < RT; ++i)
#pragma unroll
    for (int j = 0; j < CT; ++j) acc[i][j] = (f32x4){0.f, 0.f, 0.f, 0.f};

  for (int k0 = kb; k0 < kb + Kslice; k0 += BK) {
    __syncthreads();
#pragma unroll
    for (int ii = 0; ii < BM / 64; ++ii) {
      int idx = t + ii * 256;
      int row = idx >> 2, seg = idx & 3;
      size_t go = (size_t)(bm + row) * ldab + k0 + seg * 8;
      gl_lds16(Ah + go, &As[0][idx * 8]);
      gl_lds16(Al + go, &As[1][idx * 8]);
    }
#pragma unroll
    for (int ii = 0; ii < 2; ++ii) {
      int idx = t + ii * 256;
      int row = idx >> 2, seg = idx & 3;
      size_t go = (size_t)(bn + row) * ldab + k0 + seg * 8;  // rows past N read
      gl_lds16(Bh + go, &Bs[0][idx * 8]);                    // adjacent valid plane
      gl_lds16(Bl + go, &Bs[1][idx * 8]);
    }
    __syncthreads();

    short8 ah[RT], al[RT], bh[CT], bl[CT];
#pragma unroll
    for (int i = 0; i < RT; ++i) {
      int off = (r0 + i * 16 + ml) * BK + g4 * 8;
      ah[i] = *(const short8*)&As[0][off];
      al[i] = *(const short8*)&As[1][off];
    }
#pragma unroll
    for (int j = 0; j < CT; ++j) {
      int off = (c0 + j * 16 + ml) * BK + g4 * 8;
      bh[j] = *(const short8*)&Bs[0][off];
      bl[j] = *(const short8*)&Bs[1][off];
    }
#pragma unroll
    for (int i = 0; i < RT; ++i)
#pragma unroll
      for (int j = 0; j < CT; ++j) {
        acc[i][j] = __builtin_amdgcn_mfma_f32_16x16x32_bf16(ah[i], bh[j], acc[i][j], 0, 0, 0);
        acc[i][j] = __builtin_amdgcn_mfma_f32_16x16x32_bf16(ah[i], bl[j], acc[i][j], 0, 0, 0);
        acc[i][j] = __builtin_amdgcn_mfma_f32_16x16x32_bf16(al[i], bh[j], acc[i][j], 0, 0, 0);
      }
  }

#pragma unroll
  for (int i = 0; i < RT; ++i)
#pragma unroll
    for (int j = 0; j < CT; ++j) {
      int col = bn + c0 + j * 16 + ml;
      if (col < N) {
        int rowb = bm + r0 + i * 16 + g4 * 4;
#pragma unroll
        for (int r = 0; r < 4; ++r)
          C[(size_t)(rowb + r) * ldc + col] = acc[i][j][r];
      }
    }
}

// ---------------- combine split-K partials: out = P0 + P1 ----------------
__global__ void add_out(const float* __restrict__ P, float* __restrict__ out, int n4) {
  int i = blockIdx.x * 256 + threadIdx.x;
  if (i >= n4) return;
  float4 a = ((const float4*)P)[i];
  float4 b = ((const float4*)(P + (size_t)SEQLEN * D_MODEL))[i];
  ((float4*)out)[i] = make_float4(a.x + b.x, a.y + b.y, a.z + b.z, a.w + b.w);
}

// ---------------- depthwise causal conv(4) + bias + SiLU, one batch ----------------
__global__ void conv_silu(const float* __restrict__ xbcdt,
                          const float* __restrict__ cw,
                          const float* __restrict__ cb,
                          float* __restrict__ xc) {
  int idx = blockIdx.x * blockDim.x + threadIdx.x;
  if (idx >= SEQLEN * CONV_DIM) return;
  int c = idx % CONV_DIM;
  int l = idx / CONV_DIM;
  const float w0 = cw[c * 4 + 0], w1 = cw[c * 4 + 1], w2 = cw[c * 4 + 2], w3 = cw[c * 4 + 3];
  const float* base = xbcdt + (size_t)l * XBC_LD + c;
  float acc = cb[c];
  if (l >= 3) acc = fmaf(w0, base[-(ptrdiff_t)3 * XBC_LD], acc);
  if (l >= 2) acc = fmaf(w1, base[-(ptrdiff_t)2 * XBC_LD], acc);
  if (l >= 1) acc = fmaf(w2, base[-(ptrdiff_t)1 * XBC_LD], acc);
  acc = fmaf(w3, base[0], acc);
  float sig = 1.f / (1.f + expf(-acc));
  xc[idx] = acc * sig;
}

// =================== SSD chunked scan on MFMA (dt softplus fused) ===================

// ---------------- pass A (SSD): per-chunk local state via MFMA ----------------
__launch_bounds__(256, 2)
__global__ void passA_ssd(const float* __restrict__ xc,
                          const float* __restrict__ xbcdt,
                          const float* __restrict__ dt_bias,
                          const float* __restrict__ A_log,
                          float* __restrict__ Sc, float* __restrict__ Pc) {
  const int blk = blockIdx.x;
  const int c   = blk & (NCHUNK - 1);
  const int h   = blk >> 5;
  const int l0  = c * LCHUNK;
  const int t   = threadIdx.x;
  const int wave = t >> 6, lane = t & 63;
  const int ml = lane & 15, g4 = lane >> 4;
  const float Ah = -expf(A_log[h]);

  __shared__ float cum[LCHUNK];
  __shared__ ushort Xt[2][LCHUNK * 40];   // X^T slab: [p][s], stride 40
  __shared__ ushort Bt[2][D_STATE * 40];  // (diag(w)B)^T slab: [n][s]

  // inclusive prefix of softplus(dt_raw + bias) * Ah
  if (t < LCHUNK) {
    float xv = xbcdt[(size_t)(l0 + t) * XBC_LD + DT_OFF + h] + dt_bias[h];
    float sp = (xv > 20.f) ? xv : log1pf(expf(xv));
    cum[t] = sp * Ah;
  }
  __syncthreads();
  for (int off = 1; off < LCHUNK; off <<= 1) {
    float v = (t < LCHUNK && t >= off) ? cum[t - off] : 0.f;
    __syncthreads();
    if (t < LCHUNK) cum[t] += v;
    __syncthreads();
  }
  const float cend = cum[LCHUNK - 1];

  f32x4 acc[2][4];                       // wave: 2 p-tiles x 4 n-tiles
#pragma unroll
  for (int i = 0; i < 2; ++i)
#pragma unroll
    for (int j = 0; j < 4; ++j) acc[i][j] = (f32x4){0.f, 0.f, 0.f, 0.f};
  const int p0 = wave * 32;

  for (int slab = 0; slab < 4; ++slab) {
    __syncthreads();
    for (int i = 0; i < 4; ++i) {
      int q = t + i * 256;
      int s = q >> 5, p4 = (q & 31) * 4;
      const float* src = xc + (size_t)(l0 + slab * 32 + s) * CONV_DIM + h * HEADDIM + p4;
      float4 v = *(const float4*)src;
      float vv[4] = {v.x, v.y, v.z, v.w};
#pragma unroll
      for (int j = 0; j < 4; ++j) {
        ushort hh = f2bf(vv[j]);
        Xt[0][(p4 + j) * 40 + s] = hh;
        Xt[1][(p4 + j) * 40 + s] = f2bf(vv[j] - bf2f(hh));
      }
    }
    for (int i = 0; i < 2; ++i) {
      int q = t + i * 256;
      int s = q >> 4, n4 = (q & 15) * 4;
      float w = __expf(cend - cum[slab * 32 + s]);
      const float* src = xc + (size_t)(l0 + slab * 32 + s) * CONV_DIM + D_INNER + n4;
      float4 v = *(const float4*)src;
      float vv[4] = {v.x * w, v.y * w, v.z * w, v.w * w};
#pragma unroll
      for (int j = 0; j < 4; ++j) {
        ushort hh = f2bf(vv[j]);
        Bt[0][(n4 + j) * 40 + s] = hh;
        Bt[1][(n4 + j) * 40 + s] = f2bf(vv[j] - bf2f(hh));
      }
    }
    __syncthreads();

    short8 xa_h[2], xa_l[2];
#pragma unroll
    for (int pi = 0; pi < 2; ++pi) {
      int off = (p0 + pi * 16 + ml) * 40 + g4 * 8;
      xa_h[pi] = *(const short8*)&Xt[0][off];
      xa_l[pi] = *(const short8*)&Xt[1][off];
    }
#pragma unroll
    for (int ni = 0; ni < 4; ++ni) {
      int off = (ni * 16 + ml) * 40 + g4 * 8;
      short8 bh = *(const short8*)&Bt[0][off];
      short8 bl = *(const short8*)&Bt[1][off];
#pragma unroll
      for (int pi = 0; pi < 2; ++pi) {
        acc[pi][ni] = __builtin_amdgcn_mfma_f32_16x16x32_bf16(xa_h[pi], bh, acc[pi][ni], 0, 0, 0);
        acc[pi][ni] = __builtin_amdgcn_mfma_f32_16x16x32_bf16(xa_h[pi], bl, acc[pi][ni], 0, 0, 0);
        acc[pi][ni] = __builtin_amdgcn_mfma_f32_16x16x32_bf16(xa_l[pi], bh, acc[pi][ni], 0, 0, 0);
      }
    }
  }

  float* S = Sc + (size_t)blk * (HEADDIM * D_STATE);
#pragma unroll
  for (int pi = 0; pi < 2; ++pi)
#pragma unroll
    for (int ni = 0; ni < 4; ++ni) {
      int n = ni * 16 + ml;
#pragma unroll
      for (int r = 0; r < 4; ++r) {
        int p = p0 + pi * 16 + g4 * 4 + r;
        S[(size_t)p * D_STATE + n] = acc[pi][ni][r];
      }
    }
  if (t == 0) Pc[blk] = __expf(cend);
}

// ---------------- pass B: exclusive prefix over chunks ----------------
__global__ void scan_passB(float* __restrict__ Sc, const float* __restrict__ Pc) {
  const int h = blockIdx.x;
  const int e = blockIdx.y * 512 + threadIdx.x;
  const size_t hb = (size_t)h * NCHUNK;
  float st = 0.f;
  for (int c = 0; c < NCHUNK; ++c) {
    size_t idx = (hb + c) * (HEADDIM * D_STATE) + e;
    float P = Pc[hb + c];
    float v = Sc[idx];
    Sc[idx] = st;
    st = fmaf(P, st, v);
  }
}

// ---------------- pass C (SSD): intra-chunk attention + inter-chunk term ----------
__launch_bounds__(256, 2)
__global__ void passC_ssd(const float* __restrict__ xc,
                          const float* __restrict__ dt_bias,
                          const float* __restrict__ A_log,
                          const float* __restrict__ Dp,
                          const float* __restrict__ Sc,     // exclusive prefix states
                          float* __restrict__ xbcdt) {
  const int blk = blockIdx.x;
  const int c   = blk & (NCHUNK - 1);
  const int h   = blk >> 5;
  const int l0  = c * LCHUNK;
  const int t   = threadIdx.x;
  const int wave = t >> 6, lane = t & 63;
  const int ml = lane & 15, g4 = lane >> 4;
  const float Ah = -expf(A_log[h]);
  const float Dh = Dp[h];

  __shared__ float cum[LCHUNK];
  __shared__ ushort Csl[2][2][LCHUNK * 32];  // C k-slabs [n-slab][hi/lo][t][32]
  __shared__ ushort Bsl[2][2][32 * 32];      // B s-slab  [n-slab][hi/lo][s][32]
  __shared__ ushort Msl[2][LCHUNK * 32];     // masked-decay matrix slab [t][32]
  __shared__ ushort Xt[2][LCHUNK * 40];      // X^T (or S_init) slab [p][k], stride 40

  if (t < LCHUNK) {
    float xv = xbcdt[(size_t)(l0 + t) * XBC_LD + DT_OFF + h] + dt_bias[h];
    float sp = (xv > 20.f) ? xv : log1pf(expf(xv));
    cum[t] = sp * Ah;
  }
  __syncthreads();
  for (int off = 1; off < LCHUNK; off <<= 1) {
    float v = (t < LCHUNK && t >= off) ? cum[t - off] : 0.f;
    __syncthreads();
    if (t < LCHUNK) cum[t] += v;
    __syncthreads();
  }

  // stage C (resident): 128 rows x 64 cols -> two 32-wide k-slabs, split hi/lo
  {
    int row = t >> 1, half = t & 1;
    const float* src = xc + (size_t)(l0 + row) * CONV_DIM + D_INNER + D_STATE + half * 32;
    ushort* dh = &Csl[half][0][row * 32];
    ushort* dl = &Csl[half][1][row * 32];
#pragma unroll
    for (int j = 0; j < 32; j += 4) {
      float4 v = *(const float4*)(src + j);
      ushort h0 = f2bf(v.x), h1 = f2bf(v.y), h2 = f2bf(v.z), h3 = f2bf(v.w);
      *(ushort4*)(dh + j) = make_ushort4(h0, h1, h2, h3);
      *(ushort4*)(dl + j) = make_ushort4(f2bf(v.x - bf2f(h0)), f2bf(v.y - bf2f(h1)),
                                         f2bf(v.z - bf2f(h2)), f2bf(v.w - bf2f(h3)));
    }
  }

  f32x4 accY[2][8];                          // wave: 2 t-tiles x 8 p-tiles
#pragma unroll
  for (int i = 0; i < 2; ++i)
#pragma unroll
    for (int j = 0; j < 8; ++j) accY[i][j] = (f32x4){0.f, 0.f, 0.f, 0.f};
  const int t0 = wave * 32;

  // ---- intra-chunk: 4 s-slabs ----
  for (int slab = 0; slab < 4; ++slab) {
    __syncthreads();
    for (int i = 0; i < 2; ++i) {
      int q = t + i * 256;
      int s = q >> 4, c4 = (q & 15) * 4;
      const float* src = xc + (size_t)(l0 + slab * 32 + s) * CONV_DIM + D_INNER + c4;
      float4 v = *(const float4*)src;
      int ks = c4 >> 5, jj = c4 & 31;
      ushort h0 = f2bf(v.x), h1 = f2bf(v.y), h2 = f2bf(v.z), h3 = f2bf(v.w);
      *(ushort4*)&Bsl[ks][0][s * 32 + jj] = make_ushort4(h0, h1, h2, h3);
      *(ushort4*)&Bsl[ks][1][s * 32 + jj] =
          make_ushort4(f2bf(v.x - bf2f(h0)), f2bf(v.y - bf2f(h1)),
                       f2bf(v.z - bf2f(h2)), f2bf(v.w - bf2f(h3)));
    }
    for (int i = 0; i < 4; ++i) {
      int q = t + i * 256;
      int s = q >> 5, p4 = (q & 31) * 4;
      const float* src = xc + (size_t)(l0 + slab * 32 + s) * CONV_DIM + h * HEADDIM + p4;
      float4 v = *(const float4*)src;
      float vv[4] = {v.x, v.y, v.z, v.w};
#pragma unroll
      for (int j = 0; j < 4; ++j) {
        ushort hh = f2bf(vv[j]);
        Xt[0][(p4 + j) * 40 + s] = hh;
        Xt[1][(p4 + j) * 40 + s] = f2bf(vv[j] - bf2f(hh));
      }
    }
    __syncthreads();

    // phase 1: G = C . B^T for this slab (K = 64, two 32-ksteps)
    f32x4 g[2][2];
#pragma unroll
    for (int i = 0; i < 2; ++i)
#pragma unroll
      for (int j = 0; j < 2; ++j) g[i][j] = (f32x4){0.f, 0.f, 0.f, 0.f};
#pragma unroll
    for (int ks = 0; ks < 2; ++ks) {
      short8 ca_h[2], ca_l[2];
#pragma unroll
      for (int ti = 0; ti < 2; ++ti) {
        int off = (t0 + ti * 16 + ml) * 32 + g4 * 8;
        ca_h[ti] = *(const short8*)&Csl[ks][0][off];
        ca_l[ti] = *(const short8*)&Csl[ks][1][off];
      }
#pragma unroll
      for (int si = 0; si < 2; ++si) {
        int off = (si * 16 + ml) * 32 + g4 * 8;
        short8 bh = *(const short8*)&Bsl[ks][0][off];
        short8 bl = *(const short8*)&Bsl[ks][1][off];
#pragma unroll
        for (int ti = 0; ti < 2; ++ti) {
          g[ti][si] = __builtin_amdgcn_mfma_f32_16x16x32_bf16(ca_h[ti], bh, g[ti][si], 0, 0, 0);
          g[ti][si] = __builtin_amdgcn_mfma_f32_16x16x32_bf16(ca_h[ti], bl, g[ti][si], 0, 0, 0);
          g[ti][si] = __builtin_amdgcn_mfma_f32_16x16x32_bf16(ca_l[ti], bh, g[ti][si], 0, 0, 0);
        }
      }
    }
    // mask + decay + split -> Msl
#pragma unroll
    for (int ti = 0; ti < 2; ++ti)
#pragma unroll
      for (int si = 0; si < 2; ++si) {
        int sl = si * 16 + ml;
        int sg = slab * 32 + sl;
#pragma unroll
        for (int r = 0; r < 4; ++r) {
          int tg = t0 + ti * 16 + g4 * 4 + r;
          float coeff = (sg <= tg) ? __expf(cum[tg] - cum[sg]) : 0.f;
          float val = g[ti][si][r] * coeff;
          ushort hh = f2bf(val);
          Msl[0][tg * 32 + sl] = hh;
          Msl[1][tg * 32 + sl] = f2bf(val - bf2f(hh));
        }
      }
    __syncthreads();
    // phase 2: Y += M . X^T
    {
      short8 ma_h[2], ma_l[2];
#pragma unroll
      for (int ti = 0; ti < 2; ++ti) {
        int off = (t0 + ti * 16 + ml) * 32 + g4 * 8;
        ma_h[ti] = *(const short8*)&Msl[0][off];
        ma_l[ti] = *(const short8*)&Msl[1][off];
      }
#pragma unroll
      for (int pi = 0; pi < 8; ++pi) {
        int off = (pi * 16 + ml) * 40 + g4 * 8;
        short8 xh = *(const short8*)&Xt[0][off];
        short8 xl = *(const short8*)&Xt[1][off];
#pragma unroll
        for (int ti = 0; ti < 2; ++ti) {
          accY[ti][pi] = __builtin_amdgcn_mfma_f32_16x16x32_bf16(ma_h[ti], xh, accY[ti][pi], 0, 0, 0);
          accY[ti][pi] = __builtin_amdgcn_mfma_f32_16x16x32_bf16(ma_h[ti], xl, accY[ti][pi], 0, 0, 0);
          accY[ti][pi] = __builtin_amdgcn_mfma_f32_16x16x32_bf16(ma_l[ti], xh, accY[ti][pi], 0, 0, 0);
        }
      }
    }
  }

  // ---- inter-chunk: Y += diag(exp(cum)) C . S_init  (K = 64, two 32-slabs) ----
  const float* S = Sc + (size_t)blk * (HEADDIM * D_STATE);
  for (int ns = 0; ns < 2; ++ns) {
    __syncthreads();
    for (int i = 0; i < 4; ++i) {
      int q = t + i * 256;
      int p = q >> 3, j4 = (q & 7) * 4;
      float4 v = *(const float4*)(S + (size_t)p * D_STATE + ns * 32 + j4);
      float vv[4] = {v.x, v.y, v.z, v.w};
      ushort hh0 = f2bf(vv[0]), hh1 = f2bf(vv[1]), hh2 = f2bf(vv[2]), hh3 = f2bf(vv[3]);
      *(ushort4*)&Xt[0][p * 40 + j4] = make_ushort4(hh0, hh1, hh2, hh3);
      *(ushort4*)&Xt[1][p * 40 + j4] =
          make_ushort4(f2bf(vv[0] - bf2f(hh0)), f2bf(vv[1] - bf2f(hh1)),
                       f2bf(vv[2] - bf2f(hh2)), f2bf(vv[3] - bf2f(hh3)));
    }
    {
      int row = t >> 1, j0 = (t & 1) * 16;
      float e = __expf(cum[row]);
#pragma unroll
      for (int j = 0; j < 16; ++j) {
        int idx = row * 32 + j0 + j;
        float cv = bf2f(Csl[ns][0][idx]) + bf2f(Csl[ns][1][idx]);
        float val = cv * e;
        ushort hh = f2bf(val);
        Msl[0][idx] = hh;
        Msl[1][idx] = f2bf(val - bf2f(hh));
      }
    }
    __syncthreads();
    {
      short8 ma_h[2], ma_l[2];
#pragma unroll
      for (int ti = 0; ti < 2; ++ti) {
        int off = (t0 + ti * 16 + ml) * 32 + g4 * 8;
        ma_h[ti] = *(const short8*)&Msl[0][off];
        ma_l[ti] = *(const short8*)&Msl[1][off];
      }
#pragma unroll
      for (int pi = 0; pi < 8; ++pi) {
        int off = (pi * 16 + ml) * 40 + g4 * 8;
        short8 xh = *(const short8*)&Xt[0][off];
        short8 xl = *(const short8*)&Xt[1][off];
#pragma unroll
        for (int ti = 0; ti < 2; ++ti) {
          accY[ti][pi] = __builtin_amdgcn_mfma_f32_16x16x32_bf16(ma_h[ti], xh, accY[ti][pi], 0, 0, 0);
          accY[ti][pi] = __builtin_amdgcn_mfma_f32_16x16x32_bf16(ma_h[ti], xl, accY[ti][pi], 0, 0, 0);
          accY[ti][pi] = __builtin_amdgcn_mfma_f32_16x16x32_bf16(ma_l[ti], xh, accY[ti][pi], 0, 0, 0);
        }
      }
    }
  }

  // ---- epilogue: y = accY + D*x into xbcdt cols [0,2048) ----
#pragma unroll
  for (int ti = 0; ti < 2; ++ti)
#pragma unroll
    for (int pi = 0; pi < 8; ++pi) {
      int p = pi * 16 + ml;
#pragma unroll
      for (int r = 0; r < 4; ++r) {
        int l = l0 + t0 + ti * 16 + g4 * 4 + r;
        float x = xc[(size_t)l * CONV_DIM + h * HEADDIM + p];
        xbcdt[(size_t)l * XBC_LD + h * HEADDIM + p] = accY[ti][pi][r] + Dh * x;
      }
    }
}

// ------- RMSNorm + sigmoid(z) gate, emits gated y as bf16 hi/lo planes -------
__launch_bounds__(256)
__global__ void rmsnorm_gate_split(const float* __restrict__ xbcdt,
                                   const float* __restrict__ zbuf,
                                   const float* __restrict__ rms_w,
                                   ushort* __restrict__ yh, ushort* __restrict__ yl) {
  const int row = blockIdx.x;
  const int t   = threadIdx.x;
  const float* y = xbcdt + (size_t)row * XBC_LD;
  const float* z = zbuf  + (size_t)row * D_INNER;

  float4 a  = *(const float4*)(y + t * 8);
  float4 bq = *(const float4*)(y + t * 8 + 4);
  float ss = a.x * a.x + a.y * a.y + a.z * a.z + a.w * a.w +
             bq.x * bq.x + bq.y * bq.y + bq.z * bq.z + bq.w * bq.w;
#pragma unroll
  for (int off = 32; off > 0; off >>= 1) ss += __shfl_down(ss, off);
  __shared__ float red[4];
  if ((t & 63) == 0) red[t >> 6] = ss;
  __syncthreads();
  float tot = red[0] + red[1] + red[2] + red[3];
  float scale = rsqrtf(tot * (1.f / (float)D_INNER) + RMS_EPS);

  float vy[8] = {a.x, a.y, a.z, a.w, bq.x, bq.y, bq.z, bq.w};
  ushort hh[8], ll[8];
#pragma unroll
  for (int jj = 0; jj < 8; ++jj) {
    int col = t * 8 + jj;
    float zv = z[col];
    float g = 1.f / (1.f + expf(-zv));
    float v = vy[jj] * scale * rms_w[col] * g;
    hh[jj] = f2bf(v);
    ll[jj] = f2bf(v - bf2f(hh[jj]));
  }
  size_t o = (size_t)row * D_INNER + t * 8;
  *(ushort4*)(yh + o)     = make_ushort4(hh[0], hh[1], hh[2], hh[3]);
  *(ushort4*)(yh + o + 4) = make_ushort4(hh[4], hh[5], hh[6], hh[7]);
  *(ushort4*)(yl + o)     = make_ushort4(ll[0], ll[1], ll[2], ll[3]);
  *(ushort4*)(yl + o + 4) = make_ushort4(ll[4], ll[5], ll[6], ll[7]);
}

// ---------------- launch ----------------
// ws (floats): xbcdt 8,978,432 | xc 8,912,896 | Pc 512 | Sc 4,194,304
//            | u planes 4,194,304 | w1 planes 4,341,760 | w2 planes 2,097,152
//            = 32,719,360 floats = 130.9 MB (<= R5's passing 131.1 MB).
// Aliases: zbuf & out-partials in xc region (conv data dead by then);
//          y planes overlay [Sc .. u planes) (both dead by rmsnorm).
extern "C" void kernel_launch(void* const* d_in, const int* in_sizes, int n_in,
                              void* d_out, int out_size, void* d_ws, size_t ws_size,
                              hipStream_t stream) {
  const float* u         = (const float*)d_in[0];
  const float* in_proj_w = (const float*)d_in[1];
  const float* conv_w    = (const float*)d_in[2];
  const float* conv_b    = (const float*)d_in[3];
  const float* dt_bias   = (const float*)d_in[4];
  const float* A_log     = (const float*)d_in[5];
  const float* Dp        = (const float*)d_in[6];
  const float* rms_w     = (const float*)d_in[7];
  const float* out_w     = (const float*)d_in[8];
  float* out = (float*)d_out;

  float* ws    = (float*)d_ws;
  float* xbcdt = ws;                                           // [4096, 2192]
  float* xc    = xbcdt + (size_t)SEQLEN * XBC_LD;              // [4096, 2176]
  float* Pc    = xc    + (size_t)SEQLEN * CONV_DIM;            // [512]
  float* Sc    = Pc    + 512;                                  // [512, 8192]
  ushort* uh   = (ushort*)(Sc + (size_t)NHEADS * NCHUNK * HEADDIM * D_STATE);
  ushort* ul   = uh  + (size_t)SEQLEN * D_MODEL;
  ushort* w1h  = ul  + (size_t)SEQLEN * D_MODEL;
  ushort* w1l  = w1h + (size_t)D_IN_PROJ * D_MODEL;
  ushort* w2h  = w1l + (size_t)D_IN_PROJ * D_MODEL;
  ushort* w2l  = w2h + (size_t)D_MODEL * D_INNER;
  ushort* yh   = (ushort*)Sc;                                  // overlay Sc + u planes
  ushort* yl   = yh + (size_t)SEQLEN * D_INNER;
  float* zbuf  = xc;                                           // z after scan
  float* Opart = xc;                                           // split-K partials [2][4096][1024]

  // weight splits (once per call)
  {
    int n4 = D_IN_PROJ * D_MODEL / 4;
    cvt_split<<<(n4 + 255) / 256, 256, 0, stream>>>(in_proj_w, w1h, w1l, n4);
    int m4 = D_MODEL * D_INNER / 4;
    cvt_split<<<(m4 + 255) / 256, 256, 0, stream>>>(out_w, w2h, w2l, m4);
  }

  for (int b = 0; b < BATCH; ++b) {
    const float* u_b  = u   + (size_t)b * SEQLEN * D_MODEL;
    float*      out_b = out + (size_t)b * SEQLEN * D_MODEL;

    // 0) split u_b -> bf16 planes
    {
      int n4 = SEQLEN * D_MODEL / 4;
      cvt_split<<<(n4 + 255) / 256, 256, 0, stream>>>(u_b, uh, ul, n4);
    }

    // 1) xBC|dt GEMM: xbcdt[4096,2192] = u * in_proj_w[2048:4240]^T
    {
      const ushort* bh = w1h + (size_t)D_INNER * D_MODEL;
      const ushort* bl = w1l + (size_t)D_INNER * D_MODEL;
      dim3 g((N_XBC + 127) / 128, SEQLEN / 128, 1);
      gemm_bf16p<128><<<g, 256, 0, stream>>>(uh, ul, bh, bl,
                                             xbcdt, XBC_LD, SEQLEN, N_XBC,
                                             D_MODEL, D_MODEL);
    }

    // 2) depthwise conv + SiLU (dt softplus now fused into scan passes)
    conv_silu<<<(SEQLEN * CONV_DIM + 255) / 256, 256, 0, stream>>>(xbcdt, conv_w, conv_b, xc);

    // 3-5) SSD chunked scan on MFMA
    passA_ssd<<<NHEADS * NCHUNK, 256, 0, stream>>>(xc, xbcdt, dt_bias, A_log, Sc, Pc);
    scan_passB<<<dim3(NHEADS, (HEADDIM * D_STATE) / 512), 512, 0, stream>>>(Sc, Pc);
    passC_ssd<<<NHEADS * NCHUNK, 256, 0, stream>>>(xc, dt_bias, A_log, Dp, Sc, xbcdt);

    // 6) deferred z GEMM into the (now dead) conv buffer; last use of u planes
    {
      dim3 g(D_INNER / 128, SEQLEN / 128, 1);
      gemm_bf16p<128><<<g, 256, 0, stream>>>(uh, ul, w1h, w1l,
                                             zbuf, D_INNER, SEQLEN, D_INNER,
                                             D_MODEL, D_MODEL);
    }

    // 7) RMSNorm + gate -> y bf16 planes (overlay Sc/u planes, both dead now)
    rmsnorm_gate_split<<<SEQLEN, 256, 0, stream>>>(xbcdt, zbuf, rms_w, yh, yl);

    // 8) out GEMM, split-K=2 at full 128x128 density -> partials in xc region
    {
      dim3 g(D_MODEL / 128, SEQLEN / 128, 2);
      gemm_bf16p<128><<<g, 256, 0, stream>>>(yh, yl, w2h, w2l,
                                             Opart, D_MODEL, SEQLEN, D_MODEL,
                                             D_INNER, D_INNER / 2);
    }
    // 9) combine partials -> out_b
    add_out<<<(SEQLEN * D_MODEL / 4 + 255) / 256, 256, 0, stream>>>(Opart, out_b,
                                                                    SEQLEN * D_MODEL / 4);
  }
}

// Round 7
// 685.063 us; speedup vs baseline: 2.8108x; 1.0945x over previous
//
#include <hip/hip_runtime.h>
#include <math.h>

// ---------------- problem constants ----------------
#define D_MODEL   1024
#define D_INNER   2048
#define D_STATE   64
#define HEADDIM   128
#define NHEADS    16
#define D_CONV    4
#define CONV_DIM  2176        // D_INNER + 2*D_STATE
#define BATCH     2
#define SEQLEN    4096
#define RMS_EPS   1e-5f

// xbcdt buffer: cols [0,2048)=x (y after scan), [2048,2112)=B, [2112,2176)=C, [2176,2192)=dt
#define XBC_LD    2192
#define DT_OFF    2176
#define N_XBC     2192
#define D_IN_PROJ 4240

#define LCHUNK    128
#define NCHUNK    (SEQLEN / LCHUNK)   // 32

typedef __attribute__((ext_vector_type(8))) short short8;
typedef __attribute__((ext_vector_type(4))) float f32x4;

__device__ __forceinline__ ushort f2bf(float f) {
  unsigned u = __float_as_uint(f);
  u += 0x7fff + ((u >> 16) & 1);          // RNE
  return (ushort)(u >> 16);
}
__device__ __forceinline__ float bf2f(ushort h) {
  return __uint_as_float(((unsigned)h) << 16);
}

// async global->LDS, 16B per lane (global_load_lds_dwordx4)
__device__ __forceinline__ void gl_lds16(const ushort* g, ushort* l) {
  __builtin_amdgcn_global_load_lds(
      (const __attribute__((address_space(1))) unsigned int*)g,
      (__attribute__((address_space(3))) unsigned int*)l, 16, 0, 0);
}

// ---------------- split fp32 -> bf16 hi/lo planes ----------------
__global__ void cvt_split(const float* __restrict__ w,
                          ushort* __restrict__ hi, ushort* __restrict__ lo, int n4) {
  int i = blockIdx.x * 256 + threadIdx.x;
  if (i >= n4) return;
  float4 v = ((const float4*)w)[i];
  ushort h0 = f2bf(v.x), h1 = f2bf(v.y), h2 = f2bf(v.z), h3 = f2bf(v.w);
  ushort l0 = f2bf(v.x - bf2f(h0)), l1 = f2bf(v.y - bf2f(h1));
  ushort l2 = f2bf(v.z - bf2f(h2)), l3 = f2bf(v.w - bf2f(h3));
  ((ushort4*)hi)[i] = make_ushort4(h0, h1, h2, h3);
  ((ushort4*)lo)[i] = make_ushort4(l0, l1, l2, l3);
}

// ---------------- pure-bf16-plane split NT GEMM: C[M,N] = A[M,K] * B[N,K]^T ------
// A planes [M][ldab], B planes [N][ldab]. grid.z = split-K slice index.
// ALO=true : 3-term split  (AhBh + AhBl + AlBh) — near-fp32.
// ALO=false: 2-term split  (AhBh + AhBl)       — A effectively bf16; Al unused.
// launch_bounds(256,3): 3 blocks/CU (32KB LDS each, 96KB total) to hide the
// vmcnt(0)+barrier drain that capped R6 at MfmaUtil 32% / occupancy 16%.
template<int BM, bool ALO>
__launch_bounds__(256, 3)
__global__ void gemm_bf16p(const ushort* __restrict__ Ah, const ushort* __restrict__ Al,
                           const ushort* __restrict__ Bh, const ushort* __restrict__ Bl,
                           float* __restrict__ C, int ldc,
                           int M, int N, int ldab, int Kslice) {
  constexpr int BN = 128, BK = 32;
  constexpr int RT = BM / 32;
  constexpr int CT = 4;

  __shared__ ushort As[ALO ? 2 : 1][BM * BK];
  __shared__ ushort Bs[2][BN * BK];

  const int t    = threadIdx.x;
  const int bm   = blockIdx.y * BM;
  const int bn   = blockIdx.x * BN;
  const int kz   = blockIdx.z;
  const int kb   = kz * Kslice;
  C += (size_t)kz * M * ldc;               // partial plane for split-K
  const int wave = t >> 6, lane = t & 63;
  const int ml   = lane & 15, g4 = lane >> 4;
  const int wr   = wave & 1, wc = wave >> 1;
  const int r0   = wr * RT * 16, c0 = wc * CT * 16;

  f32x4 acc[RT][CT];
#pragma unroll
  for (int i = 0; i < RT; ++i)
#pragma unroll
    for (int j = 0; j < CT; ++j) acc[i][j] = (f32x4){0.f, 0.f, 0.f, 0.f};

  for (int k0 = kb; k0 < kb + Kslice; k0 += BK) {
    __syncthreads();
#pragma unroll
    for (int ii = 0; ii < BM / 64; ++ii) {
      int idx = t + ii * 256;
      int row = idx >> 2, seg = idx & 3;
      size_t go = (size_t)(bm + row) * ldab + k0 + seg * 8;
      gl_lds16(Ah + go, &As[0][idx * 8]);
      if (ALO) gl_lds16(Al + go, &As[ALO ? 1 : 0][idx * 8]);
    }
#pragma unroll
    for (int ii = 0; ii < 2; ++ii) {
      int idx = t + ii * 256;
      int row = idx >> 2, seg = idx & 3;
      size_t go = (size_t)(bn + row) * ldab + k0 + seg * 8;  // rows past N read
      gl_lds16(Bh + go, &Bs[0][idx * 8]);                    // adjacent valid plane
      gl_lds16(Bl + go, &Bs[1][idx * 8]);
    }
    __syncthreads();

    short8 ah[RT], al[RT], bh[CT], bl[CT];
#pragma unroll
    for (int i = 0; i < RT; ++i) {
      int off = (r0 + i * 16 + ml) * BK + g4 * 8;
      ah[i] = *(const short8*)&As[0][off];
      if (ALO) al[i] = *(const short8*)&As[ALO ? 1 : 0][off];
    }
#pragma unroll
    for (int j = 0; j < CT; ++j) {
      int off = (c0 + j * 16 + ml) * BK + g4 * 8;
      bh[j] = *(const short8*)&Bs[0][off];
      bl[j] = *(const short8*)&Bs[1][off];
    }
#pragma unroll
    for (int i = 0; i < RT; ++i)
#pragma unroll
      for (int j = 0; j < CT; ++j) {
        acc[i][j] = __builtin_amdgcn_mfma_f32_16x16x32_bf16(ah[i], bh[j], acc[i][j], 0, 0, 0);
        acc[i][j] = __builtin_amdgcn_mfma_f32_16x16x32_bf16(ah[i], bl[j], acc[i][j], 0, 0, 0);
        if (ALO)
          acc[i][j] = __builtin_amdgcn_mfma_f32_16x16x32_bf16(al[i], bh[j], acc[i][j], 0, 0, 0);
      }
  }

#pragma unroll
  for (int i = 0; i < RT; ++i)
#pragma unroll
    for (int j = 0; j < CT; ++j) {
      int col = bn + c0 + j * 16 + ml;
      if (col < N) {
        int rowb = bm + r0 + i * 16 + g4 * 4;
#pragma unroll
        for (int r = 0; r < 4; ++r)
          C[(size_t)(rowb + r) * ldc + col] = acc[i][j][r];
      }
    }
}

// ---------------- combine split-K partials: out = P0 + P1 ----------------
__global__ void add_out(const float* __restrict__ P, float* __restrict__ out, int n4) {
  int i = blockIdx.x * 256 + threadIdx.x;
  if (i >= n4) return;
  float4 a = ((const float4*)P)[i];
  float4 b = ((const float4*)(P + (size_t)SEQLEN * D_MODEL))[i];
  ((float4*)out)[i] = make_float4(a.x + b.x, a.y + b.y, a.z + b.z, a.w + b.w);
}

// ---------------- depthwise causal conv(4) + bias + SiLU, one batch ----------------
__global__ void conv_silu(const float* __restrict__ xbcdt,
                          const float* __restrict__ cw,
                          const float* __restrict__ cb,
                          float* __restrict__ xc) {
  int idx = blockIdx.x * blockDim.x + threadIdx.x;
  if (idx >= SEQLEN * CONV_DIM) return;
  int c = idx % CONV_DIM;
  int l = idx / CONV_DIM;
  const float w0 = cw[c * 4 + 0], w1 = cw[c * 4 + 1], w2 = cw[c * 4 + 2], w3 = cw[c * 4 + 3];
  const float* base = xbcdt + (size_t)l * XBC_LD + c;
  float acc = cb[c];
  if (l >= 3) acc = fmaf(w0, base[-(ptrdiff_t)3 * XBC_LD], acc);
  if (l >= 2) acc = fmaf(w1, base[-(ptrdiff_t)2 * XBC_LD], acc);
  if (l >= 1) acc = fmaf(w2, base[-(ptrdiff_t)1 * XBC_LD], acc);
  acc = fmaf(w3, base[0], acc);
  float sig = 1.f / (1.f + expf(-acc));
  xc[idx] = acc * sig;
}

// =================== SSD chunked scan on MFMA (dt softplus fused) ===================

// ---------------- pass A (SSD): per-chunk local state via MFMA ----------------
__launch_bounds__(256, 2)
__global__ void passA_ssd(const float* __restrict__ xc,
                          const float* __restrict__ xbcdt,
                          const float* __restrict__ dt_bias,
                          const float* __restrict__ A_log,
                          float* __restrict__ Sc, float* __restrict__ Pc) {
  const int blk = blockIdx.x;
  const int c   = blk & (NCHUNK - 1);
  const int h   = blk >> 5;
  const int l0  = c * LCHUNK;
  const int t   = threadIdx.x;
  const int wave = t >> 6, lane = t & 63;
  const int ml = lane & 15, g4 = lane >> 4;
  const float Ah = -expf(A_log[h]);

  __shared__ float cum[LCHUNK];
  __shared__ ushort Xt[2][LCHUNK * 40];   // X^T slab: [p][s], stride 40
  __shared__ ushort Bt[2][D_STATE * 40];  // (diag(w)B)^T slab: [n][s]

  if (t < LCHUNK) {
    float xv = xbcdt[(size_t)(l0 + t) * XBC_LD + DT_OFF + h] + dt_bias[h];
    float sp = (xv > 20.f) ? xv : log1pf(expf(xv));
    cum[t] = sp * Ah;
  }
  __syncthreads();
  for (int off = 1; off < LCHUNK; off <<= 1) {
    float v = (t < LCHUNK && t >= off) ? cum[t - off] : 0.f;
    __syncthreads();
    if (t < LCHUNK) cum[t] += v;
    __syncthreads();
  }
  const float cend = cum[LCHUNK - 1];

  f32x4 acc[2][4];                       // wave: 2 p-tiles x 4 n-tiles
#pragma unroll
  for (int i = 0; i < 2; ++i)
#pragma unroll
    for (int j = 0; j < 4; ++j) acc[i][j] = (f32x4){0.f, 0.f, 0.f, 0.f};
  const int p0 = wave * 32;

  for (int slab = 0; slab < 4; ++slab) {
    __syncthreads();
    for (int i = 0; i < 4; ++i) {
      int q = t + i * 256;
      int s = q >> 5, p4 = (q & 31) * 4;
      const float* src = xc + (size_t)(l0 + slab * 32 + s) * CONV_DIM + h * HEADDIM + p4;
      float4 v = *(const float4*)src;
      float vv[4] = {v.x, v.y, v.z, v.w};
#pragma unroll
      for (int j = 0; j < 4; ++j) {
        ushort hh = f2bf(vv[j]);
        Xt[0][(p4 + j) * 40 + s] = hh;
        Xt[1][(p4 + j) * 40 + s] = f2bf(vv[j] - bf2f(hh));
      }
    }
    for (int i = 0; i < 2; ++i) {
      int q = t + i * 256;
      int s = q >> 4, n4 = (q & 15) * 4;
      float w = __expf(cend - cum[slab * 32 + s]);
      const float* src = xc + (size_t)(l0 + slab * 32 + s) * CONV_DIM + D_INNER + n4;
      float4 v = *(const float4*)src;
      float vv[4] = {v.x * w, v.y * w, v.z * w, v.w * w};
#pragma unroll
      for (int j = 0; j < 4; ++j) {
        ushort hh = f2bf(vv[j]);
        Bt[0][(n4 + j) * 40 + s] = hh;
        Bt[1][(n4 + j) * 40 + s] = f2bf(vv[j] - bf2f(hh));
      }
    }
    __syncthreads();

    short8 xa_h[2], xa_l[2];
#pragma unroll
    for (int pi = 0; pi < 2; ++pi) {
      int off = (p0 + pi * 16 + ml) * 40 + g4 * 8;
      xa_h[pi] = *(const short8*)&Xt[0][off];
      xa_l[pi] = *(const short8*)&Xt[1][off];
    }
#pragma unroll
    for (int ni = 0; ni < 4; ++ni) {
      int off = (ni * 16 + ml) * 40 + g4 * 8;
      short8 bh = *(const short8*)&Bt[0][off];
      short8 bl = *(const short8*)&Bt[1][off];
#pragma unroll
      for (int pi = 0; pi < 2; ++pi) {
        acc[pi][ni] = __builtin_amdgcn_mfma_f32_16x16x32_bf16(xa_h[pi], bh, acc[pi][ni], 0, 0, 0);
        acc[pi][ni] = __builtin_amdgcn_mfma_f32_16x16x32_bf16(xa_h[pi], bl, acc[pi][ni], 0, 0, 0);
        acc[pi][ni] = __builtin_amdgcn_mfma_f32_16x16x32_bf16(xa_l[pi], bh, acc[pi][ni], 0, 0, 0);
      }
    }
  }

  float* S = Sc + (size_t)blk * (HEADDIM * D_STATE);
#pragma unroll
  for (int pi = 0; pi < 2; ++pi)
#pragma unroll
    for (int ni = 0; ni < 4; ++ni) {
      int n = ni * 16 + ml;
#pragma unroll
      for (int r = 0; r < 4; ++r) {
        int p = p0 + pi * 16 + g4 * 4 + r;
        S[(size_t)p * D_STATE + n] = acc[pi][ni][r];
      }
    }
  if (t == 0) Pc[blk] = __expf(cend);
}

// ---------------- pass B: exclusive prefix over chunks ----------------
__global__ void scan_passB(float* __restrict__ Sc, const float* __restrict__ Pc) {
  const int h = blockIdx.x;
  const int e = blockIdx.y * 512 + threadIdx.x;
  const size_t hb = (size_t)h * NCHUNK;
  float st = 0.f;
  for (int c = 0; c < NCHUNK; ++c) {
    size_t idx = (hb + c) * (HEADDIM * D_STATE) + e;
    float P = Pc[hb + c];
    float v = Sc[idx];
    Sc[idx] = st;
    st = fmaf(P, st, v);
  }
}

// ---------------- pass C (SSD): intra-chunk attention + inter-chunk term ----------
__launch_bounds__(256, 2)
__global__ void passC_ssd(const float* __restrict__ xc,
                          const float* __restrict__ dt_bias,
                          const float* __restrict__ A_log,
                          const float* __restrict__ Dp,
                          const float* __restrict__ Sc,     // exclusive prefix states
                          float* __restrict__ xbcdt) {
  const int blk = blockIdx.x;
  const int c   = blk & (NCHUNK - 1);
  const int h   = blk >> 5;
  const int l0  = c * LCHUNK;
  const int t   = threadIdx.x;
  const int wave = t >> 6, lane = t & 63;
  const int ml = lane & 15, g4 = lane >> 4;
  const float Ah = -expf(A_log[h]);
  const float Dh = Dp[h];

  __shared__ float cum[LCHUNK];
  __shared__ ushort Csl[2][2][LCHUNK * 32];  // C k-slabs [n-slab][hi/lo][t][32]
  __shared__ ushort Bsl[2][2][32 * 32];      // B s-slab  [n-slab][hi/lo][s][32]
  __shared__ ushort Msl[2][LCHUNK * 32];     // masked-decay matrix slab [t][32]
  __shared__ ushort Xt[2][LCHUNK * 40];      // X^T (or S_init) slab [p][k], stride 40

  if (t < LCHUNK) {
    float xv = xbcdt[(size_t)(l0 + t) * XBC_LD + DT_OFF + h] + dt_bias[h];
    float sp = (xv > 20.f) ? xv : log1pf(expf(xv));
    cum[t] = sp * Ah;
  }
  __syncthreads();
  for (int off = 1; off < LCHUNK; off <<= 1) {
    float v = (t < LCHUNK && t >= off) ? cum[t - off] : 0.f;
    __syncthreads();
    if (t < LCHUNK) cum[t] += v;
    __syncthreads();
  }

  // stage C (resident): 128 rows x 64 cols -> two 32-wide k-slabs, split hi/lo
  {
    int row = t >> 1, half = t & 1;
    const float* src = xc + (size_t)(l0 + row) * CONV_DIM + D_INNER + D_STATE + half * 32;
    ushort* dh = &Csl[half][0][row * 32];
    ushort* dl = &Csl[half][1][row * 32];
#pragma unroll
    for (int j = 0; j < 32; j += 4) {
      float4 v = *(const float4*)(src + j);
      ushort h0 = f2bf(v.x), h1 = f2bf(v.y), h2 = f2bf(v.z), h3 = f2bf(v.w);
      *(ushort4*)(dh + j) = make_ushort4(h0, h1, h2, h3);
      *(ushort4*)(dl + j) = make_ushort4(f2bf(v.x - bf2f(h0)), f2bf(v.y - bf2f(h1)),
                                         f2bf(v.z - bf2f(h2)), f2bf(v.w - bf2f(h3)));
    }
  }

  f32x4 accY[2][8];                          // wave: 2 t-tiles x 8 p-tiles
#pragma unroll
  for (int i = 0; i < 2; ++i)
#pragma unroll
    for (int j = 0; j < 8; ++j) accY[i][j] = (f32x4){0.f, 0.f, 0.f, 0.f};
  const int t0 = wave * 32;

  // ---- intra-chunk: 4 s-slabs ----
  for (int slab = 0; slab < 4; ++slab) {
    __syncthreads();
    for (int i = 0; i < 2; ++i) {
      int q = t + i * 256;
      int s = q >> 4, c4 = (q & 15) * 4;
      const float* src = xc + (size_t)(l0 + slab * 32 + s) * CONV_DIM + D_INNER + c4;
      float4 v = *(const float4*)src;
      int ks = c4 >> 5, jj = c4 & 31;
      ushort h0 = f2bf(v.x), h1 = f2bf(v.y), h2 = f2bf(v.z), h3 = f2bf(v.w);
      *(ushort4*)&Bsl[ks][0][s * 32 + jj] = make_ushort4(h0, h1, h2, h3);
      *(ushort4*)&Bsl[ks][1][s * 32 + jj] =
          make_ushort4(f2bf(v.x - bf2f(h0)), f2bf(v.y - bf2f(h1)),
                       f2bf(v.z - bf2f(h2)), f2bf(v.w - bf2f(h3)));
    }
    for (int i = 0; i < 4; ++i) {
      int q = t + i * 256;
      int s = q >> 5, p4 = (q & 31) * 4;
      const float* src = xc + (size_t)(l0 + slab * 32 + s) * CONV_DIM + h * HEADDIM + p4;
      float4 v = *(const float4*)src;
      float vv[4] = {v.x, v.y, v.z, v.w};
#pragma unroll
      for (int j = 0; j < 4; ++j) {
        ushort hh = f2bf(vv[j]);
        Xt[0][(p4 + j) * 40 + s] = hh;
        Xt[1][(p4 + j) * 40 + s] = f2bf(vv[j] - bf2f(hh));
      }
    }
    __syncthreads();

    // phase 1: G = C . B^T for this slab (K = 64, two 32-ksteps)
    f32x4 g[2][2];
#pragma unroll
    for (int i = 0; i < 2; ++i)
#pragma unroll
      for (int j = 0; j < 2; ++j) g[i][j] = (f32x4){0.f, 0.f, 0.f, 0.f};
#pragma unroll
    for (int ks = 0; ks < 2; ++ks) {
      short8 ca_h[2], ca_l[2];
#pragma unroll
      for (int ti = 0; ti < 2; ++ti) {
        int off = (t0 + ti * 16 + ml) * 32 + g4 * 8;
        ca_h[ti] = *(const short8*)&Csl[ks][0][off];
        ca_l[ti] = *(const short8*)&Csl[ks][1][off];
      }
#pragma unroll
      for (int si = 0; si < 2; ++si) {
        int off = (si * 16 + ml) * 32 + g4 * 8;
        short8 bh = *(const short8*)&Bsl[ks][0][off];
        short8 bl = *(const short8*)&Bsl[ks][1][off];
#pragma unroll
        for (int ti = 0; ti < 2; ++ti) {
          g[ti][si] = __builtin_amdgcn_mfma_f32_16x16x32_bf16(ca_h[ti], bh, g[ti][si], 0, 0, 0);
          g[ti][si] = __builtin_amdgcn_mfma_f32_16x16x32_bf16(ca_h[ti], bl, g[ti][si], 0, 0, 0);
          g[ti][si] = __builtin_amdgcn_mfma_f32_16x16x32_bf16(ca_l[ti], bh, g[ti][si], 0, 0, 0);
        }
      }
    }
    // mask + decay + split -> Msl
#pragma unroll
    for (int ti = 0; ti < 2; ++ti)
#pragma unroll
      for (int si = 0; si < 2; ++si) {
        int sl = si * 16 + ml;
        int sg = slab * 32 + sl;
#pragma unroll
        for (int r = 0; r < 4; ++r) {
          int tg = t0 + ti * 16 + g4 * 4 + r;
          float coeff = (sg <= tg) ? __expf(cum[tg] - cum[sg]) : 0.f;
          float val = g[ti][si][r] * coeff;
          ushort hh = f2bf(val);
          Msl[0][tg * 32 + sl] = hh;
          Msl[1][tg * 32 + sl] = f2bf(val - bf2f(hh));
        }
      }
    __syncthreads();
    // phase 2: Y += M . X^T
    {
      short8 ma_h[2], ma_l[2];
#pragma unroll
      for (int ti = 0; ti < 2; ++ti) {
        int off = (t0 + ti * 16 + ml) * 32 + g4 * 8;
        ma_h[ti] = *(const short8*)&Msl[0][off];
        ma_l[ti] = *(const short8*)&Msl[1][off];
      }
#pragma unroll
      for (int pi = 0; pi < 8; ++pi) {
        int off = (pi * 16 + ml) * 40 + g4 * 8;
        short8 xh = *(const short8*)&Xt[0][off];
        short8 xl = *(const short8*)&Xt[1][off];
#pragma unroll
        for (int ti = 0; ti < 2; ++ti) {
          accY[ti][pi] = __builtin_amdgcn_mfma_f32_16x16x32_bf16(ma_h[ti], xh, accY[ti][pi], 0, 0, 0);
          accY[ti][pi] = __builtin_amdgcn_mfma_f32_16x16x32_bf16(ma_h[ti], xl, accY[ti][pi], 0, 0, 0);
          accY[ti][pi] = __builtin_amdgcn_mfma_f32_16x16x32_bf16(ma_l[ti], xh, accY[ti][pi], 0, 0, 0);
        }
      }
    }
  }

  // ---- inter-chunk: Y += diag(exp(cum)) C . S_init  (K = 64, two 32-slabs) ----
  const float* S = Sc + (size_t)blk * (HEADDIM * D_STATE);
  for (int ns = 0; ns < 2; ++ns) {
    __syncthreads();
    for (int i = 0; i < 4; ++i) {
      int q = t + i * 256;
      int p = q >> 3, j4 = (q & 7) * 4;
      float4 v = *(const float4*)(S + (size_t)p * D_STATE + ns * 32 + j4);
      float vv[4] = {v.x, v.y, v.z, v.w};
      ushort hh0 = f2bf(vv[0]), hh1 = f2bf(vv[1]), hh2 = f2bf(vv[2]), hh3 = f2bf(vv[3]);
      *(ushort4*)&Xt[0][p * 40 + j4] = make_ushort4(hh0, hh1, hh2, hh3);
      *(ushort4*)&Xt[1][p * 40 + j4] =
          make_ushort4(f2bf(vv[0] - bf2f(hh0)), f2bf(vv[1] - bf2f(hh1)),
                       f2bf(vv[2] - bf2f(hh2)), f2bf(vv[3] - bf2f(hh3)));
    }
    {
      int row = t >> 1, j0 = (t & 1) * 16;
      float e = __expf(cum[row]);
#pragma unroll
      for (int j = 0; j < 16; ++j) {
        int idx = row * 32 + j0 + j;
        float cv = bf2f(Csl[ns][0][idx]) + bf2f(Csl[ns][1][idx]);
        float val = cv * e;
        ushort hh = f2bf(val);
        Msl[0][idx] = hh;
        Msl[1][idx] = f2bf(val - bf2f(hh));
      }
    }
    __syncthreads();
    {
      short8 ma_h[2], ma_l[2];
#pragma unroll
      for (int ti = 0; ti < 2; ++ti) {
        int off = (t0 + ti * 16 + ml) * 32 + g4 * 8;
        ma_h[ti] = *(const short8*)&Msl[0][off];
        ma_l[ti] = *(const short8*)&Msl[1][off];
      }
#pragma unroll
      for (int pi = 0; pi < 8; ++pi) {
        int off = (pi * 16 + ml) * 40 + g4 * 8;
        short8 xh = *(const short8*)&Xt[0][off];
        short8 xl = *(const short8*)&Xt[1][off];
#pragma unroll
        for (int ti = 0; ti < 2; ++ti) {
          accY[ti][pi] = __builtin_amdgcn_mfma_f32_16x16x32_bf16(ma_h[ti], xh, accY[ti][pi], 0, 0, 0);
          accY[ti][pi] = __builtin_amdgcn_mfma_f32_16x16x32_bf16(ma_h[ti], xl, accY[ti][pi], 0, 0, 0);
          accY[ti][pi] = __builtin_amdgcn_mfma_f32_16x16x32_bf16(ma_l[ti], xh, accY[ti][pi], 0, 0, 0);
        }
      }
    }
  }

  // ---- epilogue: y = accY + D*x into xbcdt cols [0,2048) ----
#pragma unroll
  for (int ti = 0; ti < 2; ++ti)
#pragma unroll
    for (int pi = 0; pi < 8; ++pi) {
      int p = pi * 16 + ml;
#pragma unroll
      for (int r = 0; r < 4; ++r) {
        int l = l0 + t0 + ti * 16 + g4 * 4 + r;
        float x = xc[(size_t)l * CONV_DIM + h * HEADDIM + p];
        xbcdt[(size_t)l * XBC_LD + h * HEADDIM + p] = accY[ti][pi][r] + Dh * x;
      }
    }
}

// ------- RMSNorm + sigmoid(z) gate, emits gated y as bf16 hi plane only -------
// (out GEMM is 2-term: A-lo never read, so don't compute/store it)
__launch_bounds__(256)
__global__ void rmsnorm_gate_split(const float* __restrict__ xbcdt,
                                   const float* __restrict__ zbuf,
                                   const float* __restrict__ rms_w,
                                   ushort* __restrict__ yh) {
  const int row = blockIdx.x;
  const int t   = threadIdx.x;
  const float* y = xbcdt + (size_t)row * XBC_LD;
  const float* z = zbuf  + (size_t)row * D_INNER;

  float4 a  = *(const float4*)(y + t * 8);
  float4 bq = *(const float4*)(y + t * 8 + 4);
  float ss = a.x * a.x + a.y * a.y + a.z * a.z + a.w * a.w +
             bq.x * bq.x + bq.y * bq.y + bq.z * bq.z + bq.w * bq.w;
#pragma unroll
  for (int off = 32; off > 0; off >>= 1) ss += __shfl_down(ss, off);
  __shared__ float red[4];
  if ((t & 63) == 0) red[t >> 6] = ss;
  __syncthreads();
  float tot = red[0] + red[1] + red[2] + red[3];
  float scale = rsqrtf(tot * (1.f / (float)D_INNER) + RMS_EPS);

  float vy[8] = {a.x, a.y, a.z, a.w, bq.x, bq.y, bq.z, bq.w};
  ushort hh[8];
#pragma unroll
  for (int jj = 0; jj < 8; ++jj) {
    int col = t * 8 + jj;
    float zv = z[col];
    float g = 1.f / (1.f + expf(-zv));
    float v = vy[jj] * scale * rms_w[col] * g;
    hh[jj] = f2bf(v);
  }
  size_t o = (size_t)row * D_INNER + t * 8;
  *(ushort4*)(yh + o)     = make_ushort4(hh[0], hh[1], hh[2], hh[3]);
  *(ushort4*)(yh + o + 4) = make_ushort4(hh[4], hh[5], hh[6], hh[7]);
}

// ---------------- launch ----------------
// ws layout identical to R6 (130.9 MB, known-good). yl slot now unused.
extern "C" void kernel_launch(void* const* d_in, const int* in_sizes, int n_in,
                              void* d_out, int out_size, void* d_ws, size_t ws_size,
                              hipStream_t stream) {
  const float* u         = (const float*)d_in[0];
  const float* in_proj_w = (const float*)d_in[1];
  const float* conv_w    = (const float*)d_in[2];
  const float* conv_b    = (const float*)d_in[3];
  const float* dt_bias   = (const float*)d_in[4];
  const float* A_log     = (const float*)d_in[5];
  const float* Dp        = (const float*)d_in[6];
  const float* rms_w     = (const float*)d_in[7];
  const float* out_w     = (const float*)d_in[8];
  float* out = (float*)d_out;

  float* ws    = (float*)d_ws;
  float* xbcdt = ws;                                           // [4096, 2192]
  float* xc    = xbcdt + (size_t)SEQLEN * XBC_LD;              // [4096, 2176]
  float* Pc    = xc    + (size_t)SEQLEN * CONV_DIM;            // [512]
  float* Sc    = Pc    + 512;                                  // [512, 8192]
  ushort* uh   = (ushort*)(Sc + (size_t)NHEADS * NCHUNK * HEADDIM * D_STATE);
  ushort* ul   = uh  + (size_t)SEQLEN * D_MODEL;
  ushort* w1h  = ul  + (size_t)SEQLEN * D_MODEL;
  ushort* w1l  = w1h + (size_t)D_IN_PROJ * D_MODEL;
  ushort* w2h  = w1l + (size_t)D_IN_PROJ * D_MODEL;
  ushort* w2l  = w2h + (size_t)D_MODEL * D_INNER;
  ushort* yh   = (ushort*)Sc;                                  // overlay Sc (dead)
  float* zbuf  = xc;                                           // z after scan
  float* Opart = xc;                                           // split-K partials

  // weight splits (once per call)
  {
    int n4 = D_IN_PROJ * D_MODEL / 4;
    cvt_split<<<(n4 + 255) / 256, 256, 0, stream>>>(in_proj_w, w1h, w1l, n4);
    int m4 = D_MODEL * D_INNER / 4;
    cvt_split<<<(m4 + 255) / 256, 256, 0, stream>>>(out_w, w2h, w2l, m4);
  }

  for (int b = 0; b < BATCH; ++b) {
    const float* u_b  = u   + (size_t)b * SEQLEN * D_MODEL;
    float*      out_b = out + (size_t)b * SEQLEN * D_MODEL;

    // 0) split u_b -> bf16 planes
    {
      int n4 = SEQLEN * D_MODEL / 4;
      cvt_split<<<(n4 + 255) / 256, 256, 0, stream>>>(u_b, uh, ul, n4);
    }

    // 1) xBC|dt GEMM (3-term: dt column feeds exponentials -> keep near-fp32)
    {
      const ushort* bh = w1h + (size_t)D_INNER * D_MODEL;
      const ushort* bl = w1l + (size_t)D_INNER * D_MODEL;
      dim3 g((N_XBC + 127) / 128, SEQLEN / 128, 1);
      gemm_bf16p<128, true><<<g, 256, 0, stream>>>(uh, ul, bh, bl,
                                                   xbcdt, XBC_LD, SEQLEN, N_XBC,
                                                   D_MODEL, D_MODEL);
    }

    // 2) depthwise conv + SiLU
    conv_silu<<<(SEQLEN * CONV_DIM + 255) / 256, 256, 0, stream>>>(xbcdt, conv_w, conv_b, xc);

    // 3-5) SSD chunked scan on MFMA
    passA_ssd<<<NHEADS * NCHUNK, 256, 0, stream>>>(xc, xbcdt, dt_bias, A_log, Sc, Pc);
    scan_passB<<<dim3(NHEADS, (HEADDIM * D_STATE) / 512), 512, 0, stream>>>(Sc, Pc);
    passC_ssd<<<NHEADS * NCHUNK, 256, 0, stream>>>(xc, dt_bias, A_log, Dp, Sc, xbcdt);

    // 6) deferred z GEMM (2-term: z only feeds sigmoid gate)
    {
      dim3 g(D_INNER / 128, SEQLEN / 128, 1);
      gemm_bf16p<128, false><<<g, 256, 0, stream>>>(uh, ul, w1h, w1l,
                                                    zbuf, D_INNER, SEQLEN, D_INNER,
                                                    D_MODEL, D_MODEL);
    }

    // 7) RMSNorm + gate -> y bf16 hi plane (overlay Sc, dead now)
    rmsnorm_gate_split<<<SEQLEN, 256, 0, stream>>>(xbcdt, zbuf, rms_w, yh);

    // 8) out GEMM, split-K=2, 2-term (error ~9e-4 << 0.0078 floor)
    {
      dim3 g(D_MODEL / 128, SEQLEN / 128, 2);
      gemm_bf16p<128, false><<<g, 256, 0, stream>>>(yh, yh, w2h, w2l,
                                                    Opart, D_MODEL, SEQLEN, D_MODEL,
                                                    D_INNER, D_INNER / 2);
    }
    // 9) combine partials -> out_b
    add_out<<<(SEQLEN * D_MODEL / 4 + 255) / 256, 256, 0, stream>>>(Opart, out_b,
                                                                    SEQLEN * D_MODEL / 4);
  }
}

// Round 8
// 628.369 us; speedup vs baseline: 3.0644x; 1.0902x over previous
//
#include <hip/hip_runtime.h>
#include <math.h>

// ---------------- problem constants ----------------
#define D_MODEL   1024
#define D_INNER   2048
#define D_STATE   64
#define HEADDIM   128
#define NHEADS    16
#define D_CONV    4
#define CONV_DIM  2176        // D_INNER + 2*D_STATE
#define BATCH     2
#define SEQLEN    4096
#define RMS_EPS   1e-5f

// xbcdt buffer: cols [0,2048)=x(raw), [2048,2112)=B(raw), [2112,2176)=C(raw), [2176,2192)=dt
// conv channel index == column index (x|B|C concat order matches conv_dim layout).
#define XBC_LD    2192
#define DT_OFF    2176
#define N_XBC     2192
#define D_IN_PROJ 4240

#define LCHUNK    128
#define NCHUNK    (SEQLEN / LCHUNK)   // 32

typedef __attribute__((ext_vector_type(8))) short short8;
typedef __attribute__((ext_vector_type(4))) float f32x4;

__device__ __forceinline__ ushort f2bf(float f) {
  unsigned u = __float_as_uint(f);
  u += 0x7fff + ((u >> 16) & 1);          // RNE
  return (ushort)(u >> 16);
}
__device__ __forceinline__ float bf2f(ushort h) {
  return __uint_as_float(((unsigned)h) << 16);
}
__device__ __forceinline__ void ld4(const float* p, float* d) {
  float4 v = *(const float4*)p; d[0] = v.x; d[1] = v.y; d[2] = v.z; d[3] = v.w;
}

// async global->LDS, 16B per lane (global_load_lds_dwordx4)
__device__ __forceinline__ void gl_lds16(const ushort* g, ushort* l) {
  __builtin_amdgcn_global_load_lds(
      (const __attribute__((address_space(1))) unsigned int*)g,
      (__attribute__((address_space(3))) unsigned int*)l, 16, 0, 0);
}

// ---------------- split fp32 -> bf16 hi/lo planes ----------------
__global__ void cvt_split(const float* __restrict__ w,
                          ushort* __restrict__ hi, ushort* __restrict__ lo, int n4) {
  int i = blockIdx.x * 256 + threadIdx.x;
  if (i >= n4) return;
  float4 v = ((const float4*)w)[i];
  ushort h0 = f2bf(v.x), h1 = f2bf(v.y), h2 = f2bf(v.z), h3 = f2bf(v.w);
  ushort l0 = f2bf(v.x - bf2f(h0)), l1 = f2bf(v.y - bf2f(h1));
  ushort l2 = f2bf(v.z - bf2f(h2)), l3 = f2bf(v.w - bf2f(h3));
  ((ushort4*)hi)[i] = make_ushort4(h0, h1, h2, h3);
  ((ushort4*)lo)[i] = make_ushort4(l0, l1, l2, l3);
}

// ---------------- pure-bf16-plane split NT GEMM: C[M,N] = A[M,K] * B[N,K]^T ------
// ALO=true : 3-term (AhBh + AhBl + AlBh). ALO=false: 2-term (AhBh + AhBl).
// OBF16: store output as bf16 (for z, which only feeds sigmoid).
template<int BM, bool ALO, bool OBF16>
__launch_bounds__(256, 3)
__global__ void gemm_bf16p(const ushort* __restrict__ Ah, const ushort* __restrict__ Al,
                           const ushort* __restrict__ Bh, const ushort* __restrict__ Bl,
                           float* __restrict__ C, int ldc,
                           int M, int N, int ldab, int Kslice) {
  constexpr int BN = 128, BK = 32;
  constexpr int RT = BM / 32;
  constexpr int CT = 4;

  __shared__ ushort As[ALO ? 2 : 1][BM * BK];
  __shared__ ushort Bs[2][BN * BK];

  const int t    = threadIdx.x;
  const int bm   = blockIdx.y * BM;
  const int bn   = blockIdx.x * BN;
  const int kz   = blockIdx.z;
  const int kb   = kz * Kslice;
  C += (size_t)kz * M * ldc;               // partial plane for split-K
  const int wave = t >> 6, lane = t & 63;
  const int ml   = lane & 15, g4 = lane >> 4;
  const int wr   = wave & 1, wc = wave >> 1;
  const int r0   = wr * RT * 16, c0 = wc * CT * 16;

  f32x4 acc[RT][CT];
#pragma unroll
  for (int i = 0; i < RT; ++i)
#pragma unroll
    for (int j = 0; j < CT; ++j) acc[i][j] = (f32x4){0.f, 0.f, 0.f, 0.f};

  for (int k0 = kb; k0 < kb + Kslice; k0 += BK) {
    __syncthreads();
#pragma unroll
    for (int ii = 0; ii < BM / 64; ++ii) {
      int idx = t + ii * 256;
      int row = idx >> 2, seg = idx & 3;
      size_t go = (size_t)(bm + row) * ldab + k0 + seg * 8;
      gl_lds16(Ah + go, &As[0][idx * 8]);
      if (ALO) gl_lds16(Al + go, &As[ALO ? 1 : 0][idx * 8]);
    }
#pragma unroll
    for (int ii = 0; ii < 2; ++ii) {
      int idx = t + ii * 256;
      int row = idx >> 2, seg = idx & 3;
      size_t go = (size_t)(bn + row) * ldab + k0 + seg * 8;  // rows past N read
      gl_lds16(Bh + go, &Bs[0][idx * 8]);                    // adjacent valid plane
      gl_lds16(Bl + go, &Bs[1][idx * 8]);
    }
    __syncthreads();

    short8 ah[RT], al[RT], bh[CT], bl[CT];
#pragma unroll
    for (int i = 0; i < RT; ++i) {
      int off = (r0 + i * 16 + ml) * BK + g4 * 8;
      ah[i] = *(const short8*)&As[0][off];
      if (ALO) al[i] = *(const short8*)&As[ALO ? 1 : 0][off];
    }
#pragma unroll
    for (int j = 0; j < CT; ++j) {
      int off = (c0 + j * 16 + ml) * BK + g4 * 8;
      bh[j] = *(const short8*)&Bs[0][off];
      bl[j] = *(const short8*)&Bs[1][off];
    }
#pragma unroll
    for (int i = 0; i < RT; ++i)
#pragma unroll
      for (int j = 0; j < CT; ++j) {
        acc[i][j] = __builtin_amdgcn_mfma_f32_16x16x32_bf16(ah[i], bh[j], acc[i][j], 0, 0, 0);
        acc[i][j] = __builtin_amdgcn_mfma_f32_16x16x32_bf16(ah[i], bl[j], acc[i][j], 0, 0, 0);
        if (ALO)
          acc[i][j] = __builtin_amdgcn_mfma_f32_16x16x32_bf16(al[i], bh[j], acc[i][j], 0, 0, 0);
      }
  }

#pragma unroll
  for (int i = 0; i < RT; ++i)
#pragma unroll
    for (int j = 0; j < CT; ++j) {
      int col = bn + c0 + j * 16 + ml;
      if (col < N) {
        int rowb = bm + r0 + i * 16 + g4 * 4;
#pragma unroll
        for (int r = 0; r < 4; ++r) {
          if (OBF16) ((ushort*)C)[(size_t)(rowb + r) * ldc + col] = f2bf(acc[i][j][r]);
          else       C[(size_t)(rowb + r) * ldc + col] = acc[i][j][r];
        }
      }
    }
}

// ---------------- combine split-K partials: out = P0 + P1 ----------------
__global__ void add_out(const float* __restrict__ P, float* __restrict__ out, int n4) {
  int i = blockIdx.x * 256 + threadIdx.x;
  if (i >= n4) return;
  float4 a = ((const float4*)P)[i];
  float4 b = ((const float4*)(P + (size_t)SEQLEN * D_MODEL))[i];
  ((float4*)out)[i] = make_float4(a.x + b.x, a.y + b.y, a.z + b.z, a.w + b.w);
}

// =================== SSD chunked scan on MFMA ===================
// conv(4)+SiLU is fused into the LDS staging (taps are L1/L2-hot within a block).
// D*x is folded into the intra-chunk mask diagonal: M[t][t] += D_h.

// in-wave shuffle prefix scan for cum[] (2 barriers instead of 14)
__device__ __forceinline__ void cum_scan(float* cum, float v, int t, float* carry) {
  int lane = t & 63;
#pragma unroll
  for (int off = 1; off < 64; off <<= 1) {
    float o = __shfl_up(v, off);
    if (lane >= off) v += o;
  }
  if (t == 63) *carry = v;
  __syncthreads();
  if (t >= 64 && t < LCHUNK) v += *carry;
  if (t < LCHUNK) cum[t] = v;
  __syncthreads();
}

// conv+silu at (l, col): 4 taps up rows; guards only matter in chunk 0.
__device__ __forceinline__ void conv4(const float* __restrict__ xb,
                                      const float* __restrict__ cw,
                                      const float* __restrict__ cb,
                                      int l, int col0, float* outv) {
  const float* bp = xb + (size_t)l * XBC_LD + col0;
  float r3[4], r2[4], r1[4], r0[4], bb[4];
  ld4(bp, r3);
  if (l >= 1) ld4(bp - XBC_LD, r2);     else { r2[0]=r2[1]=r2[2]=r2[3]=0.f; }
  if (l >= 2) ld4(bp - 2 * XBC_LD, r1); else { r1[0]=r1[1]=r1[2]=r1[3]=0.f; }
  if (l >= 3) ld4(bp - 3 * XBC_LD, r0); else { r0[0]=r0[1]=r0[2]=r0[3]=0.f; }
  ld4(cb + col0, bb);
#pragma unroll
  for (int j = 0; j < 4; ++j) {
    float w4[4]; ld4(cw + (col0 + j) * 4, w4);
    float a = bb[j];
    a = fmaf(w4[0], r0[j], a);
    a = fmaf(w4[1], r1[j], a);
    a = fmaf(w4[2], r2[j], a);
    a = fmaf(w4[3], r3[j], a);
    outv[j] = a / (1.f + __expf(-a));
  }
}

// ---------------- pass A: per-chunk local state via MFMA ----------------
__launch_bounds__(256, 2)
__global__ void passA_ssd(const float* __restrict__ xb,
                          const float* __restrict__ cw, const float* __restrict__ cb,
                          const float* __restrict__ dt_bias,
                          const float* __restrict__ A_log,
                          float* __restrict__ Sc, float* __restrict__ Pc) {
  const int blk = blockIdx.x;
  const int c   = blk & (NCHUNK - 1);
  const int h   = blk >> 5;
  const int l0  = c * LCHUNK;
  const int t   = threadIdx.x;
  const int wave = t >> 6, lane = t & 63;
  const int ml = lane & 15, g4 = lane >> 4;
  const float Ah = -expf(A_log[h]);

  __shared__ float cum[LCHUNK];
  __shared__ float carry;
  __shared__ ushort Xt[2][LCHUNK * 40];   // conv'd X^T slab: [p][s], stride 40
  __shared__ ushort Bt[2][D_STATE * 40];  // (diag(w)·conv'd B)^T slab: [n][s]

  {
    float v = 0.f;
    if (t < LCHUNK) {
      float xv = xb[(size_t)(l0 + t) * XBC_LD + DT_OFF + h] + dt_bias[h];
      float sp = (xv > 20.f) ? xv : log1pf(expf(xv));
      v = sp * Ah;
    }
    cum_scan(cum, v, t, &carry);
  }
  const float cend = cum[LCHUNK - 1];

  f32x4 acc[2][4];                       // wave: 2 p-tiles x 4 n-tiles
#pragma unroll
  for (int i = 0; i < 2; ++i)
#pragma unroll
    for (int j = 0; j < 4; ++j) acc[i][j] = (f32x4){0.f, 0.f, 0.f, 0.f};
  const int p0 = wave * 32;

  for (int slab = 0; slab < 4; ++slab) {
    __syncthreads();
    // X^T slab with inline conv+silu
    for (int i = 0; i < 4; ++i) {
      int q = t + i * 256;
      int s = q >> 5, p4 = (q & 31) * 4;
      int l = l0 + slab * 32 + s;
      float xv[4];
      conv4(xb, cw, cb, l, h * HEADDIM + p4, xv);
#pragma unroll
      for (int j = 0; j < 4; ++j) {
        ushort hh = f2bf(xv[j]);
        Xt[0][(p4 + j) * 40 + s] = hh;
        Xt[1][(p4 + j) * 40 + s] = f2bf(xv[j] - bf2f(hh));
      }
    }
    // (diag(w) B)^T slab with inline conv+silu
    for (int i = 0; i < 2; ++i) {
      int q = t + i * 256;
      int s = q >> 4, n4 = (q & 15) * 4;
      int l = l0 + slab * 32 + s;
      float wd = __expf(cend - cum[slab * 32 + s]);
      float bv[4];
      conv4(xb, cw, cb, l, D_INNER + n4, bv);
#pragma unroll
      for (int j = 0; j < 4; ++j) {
        float val = bv[j] * wd;
        ushort hh = f2bf(val);
        Bt[0][(n4 + j) * 40 + s] = hh;
        Bt[1][(n4 + j) * 40 + s] = f2bf(val - bf2f(hh));
      }
    }
    __syncthreads();

    short8 xa_h[2], xa_l[2];
#pragma unroll
    for (int pi = 0; pi < 2; ++pi) {
      int off = (p0 + pi * 16 + ml) * 40 + g4 * 8;
      xa_h[pi] = *(const short8*)&Xt[0][off];
      xa_l[pi] = *(const short8*)&Xt[1][off];
    }
#pragma unroll
    for (int ni = 0; ni < 4; ++ni) {
      int off = (ni * 16 + ml) * 40 + g4 * 8;
      short8 bh = *(const short8*)&Bt[0][off];
      short8 bl = *(const short8*)&Bt[1][off];
#pragma unroll
      for (int pi = 0; pi < 2; ++pi) {
        acc[pi][ni] = __builtin_amdgcn_mfma_f32_16x16x32_bf16(xa_h[pi], bh, acc[pi][ni], 0, 0, 0);
        acc[pi][ni] = __builtin_amdgcn_mfma_f32_16x16x32_bf16(xa_h[pi], bl, acc[pi][ni], 0, 0, 0);
        acc[pi][ni] = __builtin_amdgcn_mfma_f32_16x16x32_bf16(xa_l[pi], bh, acc[pi][ni], 0, 0, 0);
      }
    }
  }

  float* S = Sc + (size_t)blk * (HEADDIM * D_STATE);
#pragma unroll
  for (int pi = 0; pi < 2; ++pi)
#pragma unroll
    for (int ni = 0; ni < 4; ++ni) {
      int n = ni * 16 + ml;
#pragma unroll
      for (int r = 0; r < 4; ++r) {
        int p = p0 + pi * 16 + g4 * 4 + r;
        S[(size_t)p * D_STATE + n] = acc[pi][ni][r];
      }
    }
  if (t == 0) Pc[blk] = __expf(cend);
}

// ---------------- pass B: exclusive prefix over chunks ----------------
__global__ void scan_passB(float* __restrict__ Sc, const float* __restrict__ Pc) {
  const int h = blockIdx.x;
  const int e = blockIdx.y * 512 + threadIdx.x;
  const size_t hb = (size_t)h * NCHUNK;
  float st = 0.f;
  for (int c = 0; c < NCHUNK; ++c) {
    size_t idx = (hb + c) * (HEADDIM * D_STATE) + e;
    float P = Pc[hb + c];
    float v = Sc[idx];
    Sc[idx] = st;
    st = fmaf(P, st, v);
  }
}

// ---------------- pass C: intra-chunk attention + inter-chunk term -> y ----------
__launch_bounds__(256, 2)
__global__ void passC_ssd(const float* __restrict__ xb,
                          const float* __restrict__ cw, const float* __restrict__ cb,
                          const float* __restrict__ dt_bias,
                          const float* __restrict__ A_log,
                          const float* __restrict__ Dp,
                          const float* __restrict__ Sc,     // exclusive prefix states
                          float* __restrict__ ybuf) {       // [SEQLEN, D_INNER]
  const int blk = blockIdx.x;
  const int c   = blk & (NCHUNK - 1);
  const int h   = blk >> 5;
  const int l0  = c * LCHUNK;
  const int t   = threadIdx.x;
  const int wave = t >> 6, lane = t & 63;
  const int ml = lane & 15, g4 = lane >> 4;
  const float Ah = -expf(A_log[h]);
  const float Dh = Dp[h];

  __shared__ float cum[LCHUNK];
  __shared__ float carry;
  __shared__ ushort Csl[2][2][LCHUNK * 32];  // conv'd C k-slabs [n-slab][hi/lo][t][32]
  __shared__ ushort Bsl[2][2][32 * 32];      // conv'd B s-slab  [n-slab][hi/lo][s][32]
  __shared__ ushort Msl[2][LCHUNK * 32];     // masked-decay matrix slab [t][32]
  __shared__ ushort Xt[2][LCHUNK * 40];      // conv'd X^T (or S_init) slab, stride 40

  {
    float v = 0.f;
    if (t < LCHUNK) {
      float xv = xb[(size_t)(l0 + t) * XBC_LD + DT_OFF + h] + dt_bias[h];
      float sp = (xv > 20.f) ? xv : log1pf(expf(xv));
      v = sp * Ah;
    }
    cum_scan(cum, v, t, &carry);
  }

  // stage C (resident), inline conv: 128 rows x 64 cols -> two 32-wide k-slabs
  {
    int row = t >> 1, half = t & 1;
    int l = l0 + row;
    int colbase = D_INNER + D_STATE + half * 32;  // 2112 + half*32
#pragma unroll
    for (int j0 = 0; j0 < 32; j0 += 4) {
      float cv[4];
      conv4(xb, cw, cb, l, colbase + j0, cv);
      ushort h0 = f2bf(cv[0]), h1 = f2bf(cv[1]), h2 = f2bf(cv[2]), h3 = f2bf(cv[3]);
      *(ushort4*)&Csl[half][0][row * 32 + j0] = make_ushort4(h0, h1, h2, h3);
      *(ushort4*)&Csl[half][1][row * 32 + j0] =
          make_ushort4(f2bf(cv[0] - bf2f(h0)), f2bf(cv[1] - bf2f(h1)),
                       f2bf(cv[2] - bf2f(h2)), f2bf(cv[3] - bf2f(h3)));
    }
  }

  f32x4 accY[2][8];                          // wave: 2 t-tiles x 8 p-tiles
#pragma unroll
  for (int i = 0; i < 2; ++i)
#pragma unroll
    for (int j = 0; j < 8; ++j) accY[i][j] = (f32x4){0.f, 0.f, 0.f, 0.f};
  const int t0 = wave * 32;

  // ---- intra-chunk: 4 s-slabs ----
  for (int slab = 0; slab < 4; ++slab) {
    __syncthreads();
    // B s-slab, inline conv
    for (int i = 0; i < 2; ++i) {
      int q = t + i * 256;
      int s = q >> 4, c4 = (q & 15) * 4;
      int l = l0 + slab * 32 + s;
      float bv[4];
      conv4(xb, cw, cb, l, D_INNER + c4, bv);
      int ks = c4 >> 5, jj = c4 & 31;
      ushort h0 = f2bf(bv[0]), h1 = f2bf(bv[1]), h2 = f2bf(bv[2]), h3 = f2bf(bv[3]);
      *(ushort4*)&Bsl[ks][0][s * 32 + jj] = make_ushort4(h0, h1, h2, h3);
      *(ushort4*)&Bsl[ks][1][s * 32 + jj] =
          make_ushort4(f2bf(bv[0] - bf2f(h0)), f2bf(bv[1] - bf2f(h1)),
                       f2bf(bv[2] - bf2f(h2)), f2bf(bv[3] - bf2f(h3)));
    }
    // X^T slab, inline conv
    for (int i = 0; i < 4; ++i) {
      int q = t + i * 256;
      int s = q >> 5, p4 = (q & 31) * 4;
      int l = l0 + slab * 32 + s;
      float xv[4];
      conv4(xb, cw, cb, l, h * HEADDIM + p4, xv);
#pragma unroll
      for (int j = 0; j < 4; ++j) {
        ushort hh = f2bf(xv[j]);
        Xt[0][(p4 + j) * 40 + s] = hh;
        Xt[1][(p4 + j) * 40 + s] = f2bf(xv[j] - bf2f(hh));
      }
    }
    __syncthreads();

    // phase 1: G = C . B^T for this slab (K = 64, two 32-ksteps)
    f32x4 g[2][2];
#pragma unroll
    for (int i = 0; i < 2; ++i)
#pragma unroll
      for (int j = 0; j < 2; ++j) g[i][j] = (f32x4){0.f, 0.f, 0.f, 0.f};
#pragma unroll
    for (int ks = 0; ks < 2; ++ks) {
      short8 ca_h[2], ca_l[2];
#pragma unroll
      for (int ti = 0; ti < 2; ++ti) {
        int off = (t0 + ti * 16 + ml) * 32 + g4 * 8;
        ca_h[ti] = *(const short8*)&Csl[ks][0][off];
        ca_l[ti] = *(const short8*)&Csl[ks][1][off];
      }
#pragma unroll
      for (int si = 0; si < 2; ++si) {
        int off = (si * 16 + ml) * 32 + g4 * 8;
        short8 bh = *(const short8*)&Bsl[ks][0][off];
        short8 bl = *(const short8*)&Bsl[ks][1][off];
#pragma unroll
        for (int ti = 0; ti < 2; ++ti) {
          g[ti][si] = __builtin_amdgcn_mfma_f32_16x16x32_bf16(ca_h[ti], bh, g[ti][si], 0, 0, 0);
          g[ti][si] = __builtin_amdgcn_mfma_f32_16x16x32_bf16(ca_h[ti], bl, g[ti][si], 0, 0, 0);
          g[ti][si] = __builtin_amdgcn_mfma_f32_16x16x32_bf16(ca_l[ti], bh, g[ti][si], 0, 0, 0);
        }
      }
    }
    // mask + decay (+ D on the diagonal) + split -> Msl
#pragma unroll
    for (int ti = 0; ti < 2; ++ti)
#pragma unroll
      for (int si = 0; si < 2; ++si) {
        int sl = si * 16 + ml;
        int sg = slab * 32 + sl;
#pragma unroll
        for (int r = 0; r < 4; ++r) {
          int tg = t0 + ti * 16 + g4 * 4 + r;
          float coeff = (sg <= tg) ? __expf(cum[tg] - cum[sg]) : 0.f;
          float val = g[ti][si][r] * coeff + ((sg == tg) ? Dh : 0.f);
          ushort hh = f2bf(val);
          Msl[0][tg * 32 + sl] = hh;
          Msl[1][tg * 32 + sl] = f2bf(val - bf2f(hh));
        }
      }
    __syncthreads();
    // phase 2: Y += M . X^T
    {
      short8 ma_h[2], ma_l[2];
#pragma unroll
      for (int ti = 0; ti < 2; ++ti) {
        int off = (t0 + ti * 16 + ml) * 32 + g4 * 8;
        ma_h[ti] = *(const short8*)&Msl[0][off];
        ma_l[ti] = *(const short8*)&Msl[1][off];
      }
#pragma unroll
      for (int pi = 0; pi < 8; ++pi) {
        int off = (pi * 16 + ml) * 40 + g4 * 8;
        short8 xh = *(const short8*)&Xt[0][off];
        short8 xl = *(const short8*)&Xt[1][off];
#pragma unroll
        for (int ti = 0; ti < 2; ++ti) {
          accY[ti][pi] = __builtin_amdgcn_mfma_f32_16x16x32_bf16(ma_h[ti], xh, accY[ti][pi], 0, 0, 0);
          accY[ti][pi] = __builtin_amdgcn_mfma_f32_16x16x32_bf16(ma_h[ti], xl, accY[ti][pi], 0, 0, 0);
          accY[ti][pi] = __builtin_amdgcn_mfma_f32_16x16x32_bf16(ma_l[ti], xh, accY[ti][pi], 0, 0, 0);
        }
      }
    }
  }

  // ---- inter-chunk: Y += diag(exp(cum)) C . S_init  (K = 64, two 32-slabs) ----
  const float* S = Sc + (size_t)blk * (HEADDIM * D_STATE);
  for (int ns = 0; ns < 2; ++ns) {
    __syncthreads();
    for (int i = 0; i < 4; ++i) {
      int q = t + i * 256;
      int p = q >> 3, j4 = (q & 7) * 4;
      float4 v = *(const float4*)(S + (size_t)p * D_STATE + ns * 32 + j4);
      float vv[4] = {v.x, v.y, v.z, v.w};
      ushort hh0 = f2bf(vv[0]), hh1 = f2bf(vv[1]), hh2 = f2bf(vv[2]), hh3 = f2bf(vv[3]);
      *(ushort4*)&Xt[0][p * 40 + j4] = make_ushort4(hh0, hh1, hh2, hh3);
      *(ushort4*)&Xt[1][p * 40 + j4] =
          make_ushort4(f2bf(vv[0] - bf2f(hh0)), f2bf(vv[1] - bf2f(hh1)),
                       f2bf(vv[2] - bf2f(hh2)), f2bf(vv[3] - bf2f(hh3)));
    }
    {
      int row = t >> 1, j0 = (t & 1) * 16;
      float e = __expf(cum[row]);
#pragma unroll
      for (int j = 0; j < 16; ++j) {
        int idx = row * 32 + j0 + j;
        float cv = bf2f(Csl[ns][0][idx]) + bf2f(Csl[ns][1][idx]);
        float val = cv * e;
        ushort hh = f2bf(val);
        Msl[0][idx] = hh;
        Msl[1][idx] = f2bf(val - bf2f(hh));
      }
    }
    __syncthreads();
    {
      short8 ma_h[2], ma_l[2];
#pragma unroll
      for (int ti = 0; ti < 2; ++ti) {
        int off = (t0 + ti * 16 + ml) * 32 + g4 * 8;
        ma_h[ti] = *(const short8*)&Msl[0][off];
        ma_l[ti] = *(const short8*)&Msl[1][off];
      }
#pragma unroll
      for (int pi = 0; pi < 8; ++pi) {
        int off = (pi * 16 + ml) * 40 + g4 * 8;
        short8 xh = *(const short8*)&Xt[0][off];
        short8 xl = *(const short8*)&Xt[1][off];
#pragma unroll
        for (int ti = 0; ti < 2; ++ti) {
          accY[ti][pi] = __builtin_amdgcn_mfma_f32_16x16x32_bf16(ma_h[ti], xh, accY[ti][pi], 0, 0, 0);
          accY[ti][pi] = __builtin_amdgcn_mfma_f32_16x16x32_bf16(ma_h[ti], xl, accY[ti][pi], 0, 0, 0);
          accY[ti][pi] = __builtin_amdgcn_mfma_f32_16x16x32_bf16(ma_l[ti], xh, accY[ti][pi], 0, 0, 0);
        }
      }
    }
  }

  // ---- epilogue: y = accY (D*x already folded via mask diagonal) ----
#pragma unroll
  for (int ti = 0; ti < 2; ++ti)
#pragma unroll
    for (int pi = 0; pi < 8; ++pi) {
      int p = pi * 16 + ml;
#pragma unroll
      for (int r = 0; r < 4; ++r) {
        int l = l0 + t0 + ti * 16 + g4 * 4 + r;
        ybuf[(size_t)l * D_INNER + h * HEADDIM + p] = accY[ti][pi][r];
      }
    }
}

// ------- RMSNorm + sigmoid(z) gate (z in bf16), emits gated y as bf16 hi plane -------
__launch_bounds__(256)
__global__ void rmsnorm_gate_split(const float* __restrict__ ybuf,
                                   const ushort* __restrict__ zS,
                                   const float* __restrict__ rms_w,
                                   ushort* __restrict__ yh) {
  const int row = blockIdx.x;
  const int t   = threadIdx.x;
  const float* y  = ybuf + (size_t)row * D_INNER;
  const ushort* z = zS   + (size_t)row * D_INNER;

  float4 a  = *(const float4*)(y + t * 8);
  float4 bq = *(const float4*)(y + t * 8 + 4);
  float ss = a.x * a.x + a.y * a.y + a.z * a.z + a.w * a.w +
             bq.x * bq.x + bq.y * bq.y + bq.z * bq.z + bq.w * bq.w;
#pragma unroll
  for (int off = 32; off > 0; off >>= 1) ss += __shfl_down(ss, off);
  __shared__ float red[4];
  if ((t & 63) == 0) red[t >> 6] = ss;
  __syncthreads();
  float tot = red[0] + red[1] + red[2] + red[3];
  float scale = rsqrtf(tot * (1.f / (float)D_INNER) + RMS_EPS);

  float vy[8] = {a.x, a.y, a.z, a.w, bq.x, bq.y, bq.z, bq.w};
  ushort4 zv0 = *(const ushort4*)(z + t * 8);
  ushort4 zv1 = *(const ushort4*)(z + t * 8 + 4);
  ushort zz[8] = {zv0.x, zv0.y, zv0.z, zv0.w, zv1.x, zv1.y, zv1.z, zv1.w};
  ushort hh[8];
#pragma unroll
  for (int jj = 0; jj < 8; ++jj) {
    int col = t * 8 + jj;
    float g = 1.f / (1.f + __expf(-bf2f(zz[jj])));
    float v = vy[jj] * scale * rms_w[col] * g;
    hh[jj] = f2bf(v);
  }
  size_t o = (size_t)row * D_INNER + t * 8;
  *(ushort4*)(yh + o)     = make_ushort4(hh[0], hh[1], hh[2], hh[3]);
  *(ushort4*)(yh + o + 4) = make_ushort4(hh[4], hh[5], hh[6], hh[7]);
}

// ---------------- launch ----------------
// ws (floats, 130.9 MB total — same as R6/R7 known-good):
//   xbcdt [4096,2192] 8,978,432 | ybuf region [4096,2176] 8,912,896 | Pc 512
//   | Sc [512,8192] 4,194,304 | u planes 4,194,304 | w1 planes 4,341,760
//   | w2 planes 2,097,152
// Aliases: zS (bf16, 16.8MB) overlays Sc after passC; yh (bf16, 16.8MB) overlays
//   the u-plane region after the z GEMM; Opart overlays ybuf after rmsnorm.
extern "C" void kernel_launch(void* const* d_in, const int* in_sizes, int n_in,
                              void* d_out, int out_size, void* d_ws, size_t ws_size,
                              hipStream_t stream) {
  const float* u         = (const float*)d_in[0];
  const float* in_proj_w = (const float*)d_in[1];
  const float* conv_w    = (const float*)d_in[2];
  const float* conv_b    = (const float*)d_in[3];
  const float* dt_bias   = (const float*)d_in[4];
  const float* A_log     = (const float*)d_in[5];
  const float* Dp        = (const float*)d_in[6];
  const float* rms_w     = (const float*)d_in[7];
  const float* out_w     = (const float*)d_in[8];
  float* out = (float*)d_out;

  float* ws    = (float*)d_ws;
  float* xbcdt = ws;                                           // [4096, 2192]
  float* ybuf  = xbcdt + (size_t)SEQLEN * XBC_LD;              // [4096, 2048] (region 2176-wide)
  float* Pc    = ybuf  + (size_t)SEQLEN * CONV_DIM;            // [512]
  float* Sc    = Pc    + 512;                                  // [512, 8192]
  ushort* uh   = (ushort*)(Sc + (size_t)NHEADS * NCHUNK * HEADDIM * D_STATE);
  ushort* ul   = uh  + (size_t)SEQLEN * D_MODEL;
  ushort* w1h  = ul  + (size_t)SEQLEN * D_MODEL;
  ushort* w1l  = w1h + (size_t)D_IN_PROJ * D_MODEL;
  ushort* w2h  = w1l + (size_t)D_IN_PROJ * D_MODEL;
  ushort* w2l  = w2h + (size_t)D_MODEL * D_INNER;
  ushort* zS   = (ushort*)Sc;                                  // z bf16, after passC
  ushort* yh   = uh;                                           // gated y, after z GEMM
  float* Opart = ybuf;                                         // split-K partials, after rmsnorm

  // weight splits (once per call)
  {
    int n4 = D_IN_PROJ * D_MODEL / 4;
    cvt_split<<<(n4 + 255) / 256, 256, 0, stream>>>(in_proj_w, w1h, w1l, n4);
    int m4 = D_MODEL * D_INNER / 4;
    cvt_split<<<(m4 + 255) / 256, 256, 0, stream>>>(out_w, w2h, w2l, m4);
  }

  for (int b = 0; b < BATCH; ++b) {
    const float* u_b  = u   + (size_t)b * SEQLEN * D_MODEL;
    float*      out_b = out + (size_t)b * SEQLEN * D_MODEL;

    // 0) split u_b -> bf16 planes
    {
      int n4 = SEQLEN * D_MODEL / 4;
      cvt_split<<<(n4 + 255) / 256, 256, 0, stream>>>(u_b, uh, ul, n4);
    }

    // 1) xBC|dt GEMM (3-term: dt feeds exponentials)
    {
      const ushort* bh = w1h + (size_t)D_INNER * D_MODEL;
      const ushort* bl = w1l + (size_t)D_INNER * D_MODEL;
      dim3 g((N_XBC + 127) / 128, SEQLEN / 128, 1);
      gemm_bf16p<128, true, false><<<g, 256, 0, stream>>>(uh, ul, bh, bl,
                                                          xbcdt, XBC_LD, SEQLEN, N_XBC,
                                                          D_MODEL, D_MODEL);
    }

    // 2-4) SSD chunked scan on MFMA (conv+SiLU fused into staging; D via diagonal)
    passA_ssd<<<NHEADS * NCHUNK, 256, 0, stream>>>(xbcdt, conv_w, conv_b,
                                                   dt_bias, A_log, Sc, Pc);
    scan_passB<<<dim3(NHEADS, (HEADDIM * D_STATE) / 512), 512, 0, stream>>>(Sc, Pc);
    passC_ssd<<<NHEADS * NCHUNK, 256, 0, stream>>>(xbcdt, conv_w, conv_b,
                                                   dt_bias, A_log, Dp, Sc, ybuf);

    // 5) z GEMM (2-term, bf16 out into Sc overlay; last use of u planes)
    {
      dim3 g(D_INNER / 128, SEQLEN / 128, 1);
      gemm_bf16p<128, false, true><<<g, 256, 0, stream>>>(uh, ul, w1h, w1l,
                                                          (float*)zS, D_INNER, SEQLEN,
                                                          D_INNER, D_MODEL, D_MODEL);
    }

    // 6) RMSNorm + gate -> y bf16 hi plane (overlays u planes, dead now)
    rmsnorm_gate_split<<<SEQLEN, 256, 0, stream>>>(ybuf, zS, rms_w, yh);

    // 7) out GEMM, split-K=2, 2-term -> partials over ybuf (y dead)
    {
      dim3 g(D_MODEL / 128, SEQLEN / 128, 2);
      gemm_bf16p<128, false, false><<<g, 256, 0, stream>>>(yh, yh, w2h, w2l,
                                                           Opart, D_MODEL, SEQLEN, D_MODEL,
                                                           D_INNER, D_INNER / 2);
    }
    // 8) combine partials -> out_b
    add_out<<<(SEQLEN * D_MODEL / 4 + 255) / 256, 256, 0, stream>>>(Opart, out_b,
                                                                    SEQLEN * D_MODEL / 4);
  }
}